// Round 1
// baseline (3880.765 us; speedup 1.0000x reference)
//
#include <hip/hip_runtime.h>
#include <hip/hip_bf16.h>
#include <cstdint>
#include <cstddef>

#define N_VARS   4000
#define N_LITS   8000
#define N_CLAUSES 16000
#define N_CELLS  48000
#define DIM      128
#define N_ROUNDS 16
#define N_PROBS  8

// ---------------------------------------------------------------------------
// GEMM: out[M,N] = act(A[M,K] @ W[N,K]^T + bias[N])   (A,W,out row-major)
// 64x64 tile, 256 threads, 4x4 micro-tile per thread, LDS-staged, fp32.
// M,N,K all multiples of 64 for this problem (8000/16000, 128/512, 128/256/384).
// ---------------------------------------------------------------------------
template<bool RELU>
__global__ __launch_bounds__(256) void gemm_at(
    const float* __restrict__ A, const float* __restrict__ W,
    const float* __restrict__ bias, float* __restrict__ out,
    int M, int N, int K) {
  constexpr int BM = 64, BN = 64, BK = 64;
  __shared__ __align__(16) float As[BK][BM + 4];
  __shared__ __align__(16) float Ws[BK][BN + 4];
  const int tid = threadIdx.x;
  const int tx = tid & 15, ty = tid >> 4;
  const int m0 = blockIdx.y * BM, n0 = blockIdx.x * BN;
  float acc[4][4] = {};

  for (int k0 = 0; k0 < K; k0 += BK) {
    // stage A tile transposed: As[k][m]
#pragma unroll
    for (int j = 0; j < 4; ++j) {
      int idx = tid + j * 256;          // 0..1023
      int r = idx >> 4, c4 = idx & 15;  // row, float4-col
      float4 v = *reinterpret_cast<const float4*>(&A[(size_t)(m0 + r) * K + k0 + c4 * 4]);
      As[c4 * 4 + 0][r] = v.x; As[c4 * 4 + 1][r] = v.y;
      As[c4 * 4 + 2][r] = v.z; As[c4 * 4 + 3][r] = v.w;
    }
#pragma unroll
    for (int j = 0; j < 4; ++j) {
      int idx = tid + j * 256;
      int r = idx >> 4, c4 = idx & 15;
      float4 v = *reinterpret_cast<const float4*>(&W[(size_t)(n0 + r) * K + k0 + c4 * 4]);
      Ws[c4 * 4 + 0][r] = v.x; Ws[c4 * 4 + 1][r] = v.y;
      Ws[c4 * 4 + 2][r] = v.z; Ws[c4 * 4 + 3][r] = v.w;
    }
    __syncthreads();
#pragma unroll
    for (int kk = 0; kk < BK; ++kk) {
      float4 a = *reinterpret_cast<const float4*>(&As[kk][ty * 4]);
      float4 w = *reinterpret_cast<const float4*>(&Ws[kk][tx * 4]);
      float av[4] = {a.x, a.y, a.z, a.w};
      float wv[4] = {w.x, w.y, w.z, w.w};
#pragma unroll
      for (int i = 0; i < 4; ++i)
#pragma unroll
        for (int j = 0; j < 4; ++j)
          acc[i][j] = fmaf(av[i], wv[j], acc[i][j]);
    }
    __syncthreads();
  }

#pragma unroll
  for (int i = 0; i < 4; ++i) {
    const int m = m0 + ty * 4 + i;
#pragma unroll
    for (int j = 0; j < 4; ++j) {
      const int n = n0 + tx * 4 + j;
      float v = acc[i][j] + bias[n];
      if (RELU) v = fmaxf(v, 0.0f);
      out[(size_t)m * N + n] = v;
    }
  }
}

// ---------------------------------------------------------------------------
// SpMM + LSTM-input assembly.
// X_C[cls] = [ sum_{lit in cls} Lpre[lit] , Ch[cls] ]            ld=256
// X_L[lit] = [ sum_{cls in lit} Cpre[cls] , Lh[flip] , Lh[lit] ]  ld=384
// ---------------------------------------------------------------------------
__global__ void spmm_cls_kernel(const int* __restrict__ ptr, const int* __restrict__ col,
                                const float* __restrict__ Lpre, const float* __restrict__ Ch,
                                float* __restrict__ X) {
  const int row = blockIdx.x;
  const int t = threadIdx.x;  // 128
  const int b = ptr[row], e = ptr[row + 1];
  float s = 0.f;
  for (int j = b; j < e; ++j) s += Lpre[(size_t)col[j] * DIM + t];
  X[(size_t)row * 256 + t] = s;
  X[(size_t)row * 256 + 128 + t] = Ch[(size_t)row * DIM + t];
}

__global__ void spmm_lit_kernel(const int* __restrict__ ptr, const int* __restrict__ col,
                                const float* __restrict__ Cpre, const float* __restrict__ Lh,
                                float* __restrict__ X) {
  const int row = blockIdx.x;
  const int t = threadIdx.x;  // 128
  const int b = ptr[row], e = ptr[row + 1];
  float s = 0.f;
  for (int j = b; j < e; ++j) s += Cpre[(size_t)col[j] * DIM + t];
  const int flip = (row < N_VARS) ? row + N_VARS : row - N_VARS;
  X[(size_t)row * 384 + t] = s;
  X[(size_t)row * 384 + 128 + t] = Lh[(size_t)flip * DIM + t];
  X[(size_t)row * 384 + 256 + t] = Lh[(size_t)row * DIM + t];
}

// ---------------------------------------------------------------------------
// LSTM elementwise: gates [M,512] in (i,f,g,o) blocks of 128.
// ---------------------------------------------------------------------------
__global__ void lstm_ew_kernel(const float* __restrict__ gates,
                               float* __restrict__ h, float* __restrict__ c, int M) {
  int idx = blockIdx.x * 256 + threadIdx.x;
  if (idx >= M * DIM) return;
  int m = idx >> 7, d = idx & 127;
  const float* g = &gates[(size_t)m * 512];
  float ig = g[d], fg = g[128 + d], gg = g[256 + d], og = g[384 + d];
  float cp = c[idx];
  float si = 1.f / (1.f + expf(-ig));
  float sf = 1.f / (1.f + expf(-fg));
  float so = 1.f / (1.f + expf(-og));
  float cn = sf * cp + si * tanhf(gg);
  c[idx] = cn;
  h[idx] = so * tanhf(cn);
}

// ---------------------------------------------------------------------------
// State init: Lh = Lw[d]+Lb[d], Ch = Cw[d]+Cb[d], cells zero.
// ---------------------------------------------------------------------------
__global__ void init_state_kernel(const float* __restrict__ Lw, const float* __restrict__ Lb,
                                  const float* __restrict__ Cw, const float* __restrict__ Cb,
                                  float* __restrict__ Lh, float* __restrict__ Lc,
                                  float* __restrict__ Ch, float* __restrict__ Cc) {
  int idx = blockIdx.x * 256 + threadIdx.x;
  if (idx >= N_CLAUSES * DIM) return;
  int d = idx & 127;
  Ch[idx] = Cw[d] + Cb[d];
  Cc[idx] = 0.f;
  if (idx < N_LITS * DIM) {
    Lh[idx] = Lw[d] + Lb[d];
    Lc[idx] = 0.f;
  }
}

// ---------------------------------------------------------------------------
// Pack LSTM weights: WL[512,384] = [Lu_wih | Lu_whh], WC[512,256] = [Cu_wih | Cu_whh]
// bL = Lu_bih + Lu_bhh, bC = Cu_bih + Cu_bhh.
// ---------------------------------------------------------------------------
__global__ void pack_kernel(const float* __restrict__ Lu_wih, const float* __restrict__ Lu_whh,
                            const float* __restrict__ Lu_bih, const float* __restrict__ Lu_bhh,
                            const float* __restrict__ Cu_wih, const float* __restrict__ Cu_whh,
                            const float* __restrict__ Cu_bih, const float* __restrict__ Cu_bhh,
                            float* __restrict__ WL, float* __restrict__ WC,
                            float* __restrict__ bL, float* __restrict__ bC) {
  int idx = blockIdx.x * 256 + threadIdx.x;
  if (idx < 512 * 384) {
    int n = idx / 384, k = idx % 384;
    WL[idx] = (k < 256) ? Lu_wih[n * 256 + k] : Lu_whh[n * 128 + (k - 256)];
  }
  if (idx < 512 * 256) {
    int n = idx / 256, k = idx % 256;
    WC[idx] = (k < 128) ? Cu_wih[n * 128 + k] : Cu_whh[n * 128 + (k - 128)];
  }
  if (idx < 512) {
    bL[idx] = Lu_bih[idx] + Lu_bhh[idx];
    bC[idx] = Cu_bih[idx] + Cu_bhh[idx];
  }
}

// ---------------------------------------------------------------------------
// CSR build (both directions) from COO cells.
// ---------------------------------------------------------------------------
__global__ void count_kernel(const int* __restrict__ uidx,
                             int* __restrict__ lit_cnt, int* __restrict__ cls_cnt) {
  int i = blockIdx.x * 256 + threadIdx.x;
  if (i < N_CELLS) {
    atomicAdd(&lit_cnt[uidx[2 * i]], 1);
    atomicAdd(&cls_cnt[uidx[2 * i + 1]], 1);
  }
}

__global__ void scan_kernel(const int* __restrict__ cnt, int* __restrict__ ptr, int n) {
  __shared__ int part[1024];
  __shared__ int total;
  int t = threadIdx.x;
  int chunk = (n + 1023) >> 10;
  int lo = t * chunk, hi = min(lo + chunk, n);
  int s = 0;
  for (int i = lo; i < hi; ++i) s += cnt[i];
  part[t] = s;
  __syncthreads();
  if (t == 0) {
    int acc = 0;
    for (int i = 0; i < 1024; ++i) { int v = part[i]; part[i] = acc; acc += v; }
    total = acc;
  }
  __syncthreads();
  int acc = part[t];
  for (int i = lo; i < hi; ++i) { ptr[i] = acc; acc += cnt[i]; }
  if (t == 0) ptr[n] = total;
}

__global__ void scatter_kernel(const int* __restrict__ uidx,
                               const int* __restrict__ lit_ptr, const int* __restrict__ cls_ptr,
                               int* __restrict__ lit_fill, int* __restrict__ cls_fill,
                               int* __restrict__ lit_col, int* __restrict__ cls_col) {
  int i = blockIdx.x * 256 + threadIdx.x;
  if (i < N_CELLS) {
    int lit = uidx[2 * i], cls = uidx[2 * i + 1];
    int p = atomicAdd(&lit_fill[lit], 1);
    lit_col[lit_ptr[lit] + p] = cls;
    int q = atomicAdd(&cls_fill[cls], 1);
    cls_col[cls_ptr[cls] + q] = lit;
  }
}

// ---------------------------------------------------------------------------
// Vote: vote[l] = dot(V[l,:], w3) + b3   (one wave per row)
// ---------------------------------------------------------------------------
__global__ void vote_kernel(const float* __restrict__ V, const float* __restrict__ w3,
                            const float* __restrict__ b3, float* __restrict__ vote) {
  int row = blockIdx.x;
  int t = threadIdx.x;  // 64
  float v = V[(size_t)row * DIM + t] * w3[t] + V[(size_t)row * DIM + 64 + t] * w3[64 + t];
#pragma unroll
  for (int off = 32; off > 0; off >>= 1) v += __shfl_down(v, off, 64);
  if (t == 0) vote[row] = v + b3[0];
}

__global__ void prob_mean_kernel(const float* __restrict__ vote, float* __restrict__ out) {
  int p = blockIdx.x;   // 8
  int t = threadIdx.x;  // 256
  float s = 0.f;
  for (int i = t; i < 500; i += 256) s += vote[p * 500 + i] + vote[N_VARS + p * 500 + i];
  __shared__ float red[256];
  red[t] = s;
  __syncthreads();
  for (int off = 128; off > 0; off >>= 1) {
    if (t < off) red[t] += red[t + off];
    __syncthreads();
  }
  if (t == 0) out[p] = red[0] * (1.0f / 1000.0f);
}

// ---------------------------------------------------------------------------
extern "C" void kernel_launch(void* const* d_in, const int* in_sizes, int n_in,
                              void* d_out, int out_size, void* d_ws, size_t ws_size,
                              hipStream_t stream) {
  const int* uidx = (const int*)d_in[0];
  const float* L_init_w = (const float*)d_in[4];
  const float* L_init_b = (const float*)d_in[5];
  const float* C_init_w = (const float*)d_in[6];
  const float* C_init_b = (const float*)d_in[7];
  const float* Lmsg_w1 = (const float*)d_in[8],  *Lmsg_b1 = (const float*)d_in[9];
  const float* Lmsg_w2 = (const float*)d_in[10], *Lmsg_b2 = (const float*)d_in[11];
  const float* Lmsg_w3 = (const float*)d_in[12], *Lmsg_b3 = (const float*)d_in[13];
  const float* Cmsg_w1 = (const float*)d_in[14], *Cmsg_b1 = (const float*)d_in[15];
  const float* Cmsg_w2 = (const float*)d_in[16], *Cmsg_b2 = (const float*)d_in[17];
  const float* Cmsg_w3 = (const float*)d_in[18], *Cmsg_b3 = (const float*)d_in[19];
  const float* Lvote_w1 = (const float*)d_in[20], *Lvote_b1 = (const float*)d_in[21];
  const float* Lvote_w2 = (const float*)d_in[22], *Lvote_b2 = (const float*)d_in[23];
  const float* Lvote_w3 = (const float*)d_in[24], *Lvote_b3 = (const float*)d_in[25];
  const float* Lu_wih = (const float*)d_in[26], *Lu_whh = (const float*)d_in[27];
  const float* Lu_bih = (const float*)d_in[28], *Lu_bhh = (const float*)d_in[29];
  const float* Cu_wih = (const float*)d_in[30], *Cu_whh = (const float*)d_in[31];
  const float* Cu_bih = (const float*)d_in[32], *Cu_bhh = (const float*)d_in[33];
  float* out = (float*)d_out;

  // ---- workspace carve-up (float region, then int region) ----
  float* f = (float*)d_ws;
  size_t off = 0;
  auto falloc = [&](size_t n) { float* p = f + off; off += (n + 255) & ~(size_t)255; return p; };
  float* Lh    = falloc((size_t)N_LITS * DIM);
  float* Lc    = falloc((size_t)N_LITS * DIM);
  float* Ch    = falloc((size_t)N_CLAUSES * DIM);
  float* Cc    = falloc((size_t)N_CLAUSES * DIM);
  float* T1    = falloc((size_t)N_CLAUSES * DIM);
  float* T2    = falloc((size_t)N_CLAUSES * DIM);
  float* X     = falloc((size_t)N_CLAUSES * 256);  // also reused as [N_LITS,384]
  float* gates = falloc((size_t)N_CLAUSES * 512);
  float* WL    = falloc(512 * 384);
  float* WC    = falloc(512 * 256);
  float* bL    = falloc(512);
  float* bC    = falloc(512);
  float* vote  = falloc(N_LITS);

  int* ip = (int*)(f + off);
  size_t ioff = 0;
  auto ialloc = [&](size_t n) { int* p = ip + ioff; ioff += (n + 255) & ~(size_t)255; return p; };
  int* lit_cnt  = ialloc(N_LITS);
  int* cls_cnt  = ialloc(N_CLAUSES);
  int* lit_fill = ialloc(N_LITS);
  int* cls_fill = ialloc(N_CLAUSES);
  int* lit_ptr  = ialloc(N_LITS + 1);
  int* cls_ptr  = ialloc(N_CLAUSES + 1);
  int* lit_col  = ialloc(N_CELLS);
  int* cls_col  = ialloc(N_CELLS);

  size_t need_bytes = (off + ioff) * sizeof(float) + 4096;
  if (need_bytes > ws_size) return;  // fail loudly via wrong output rather than corrupt

  // ---- CSR build (must be redone every launch: ws is not re-poisoned) ----
  hipMemsetAsync(lit_cnt, 0, (char*)lit_ptr - (char*)lit_cnt, stream);
  count_kernel<<<(N_CELLS + 255) / 256, 256, 0, stream>>>(uidx, lit_cnt, cls_cnt);
  scan_kernel<<<1, 1024, 0, stream>>>(lit_cnt, lit_ptr, N_LITS);
  scan_kernel<<<1, 1024, 0, stream>>>(cls_cnt, cls_ptr, N_CLAUSES);
  scatter_kernel<<<(N_CELLS + 255) / 256, 256, 0, stream>>>(
      uidx, lit_ptr, cls_ptr, lit_fill, cls_fill, lit_col, cls_col);

  init_state_kernel<<<(N_CLAUSES * DIM + 255) / 256, 256, 0, stream>>>(
      L_init_w, L_init_b, C_init_w, C_init_b, Lh, Lc, Ch, Cc);
  pack_kernel<<<(512 * 384 + 255) / 256, 256, 0, stream>>>(
      Lu_wih, Lu_whh, Lu_bih, Lu_bhh, Cu_wih, Cu_whh, Cu_bih, Cu_bhh, WL, WC, bL, bC);

  auto gemm = [&](const float* A, const float* W, const float* b, float* o,
                  int M, int N, int K, bool relu) {
    dim3 grid(N / 64, M / 64);
    if (relu) gemm_at<true><<<grid, 256, 0, stream>>>(A, W, b, o, M, N, K);
    else      gemm_at<false><<<grid, 256, 0, stream>>>(A, W, b, o, M, N, K);
  };

  for (int r = 0; r < N_ROUNDS; ++r) {
    // L_pre = MLP(Lh)
    gemm(Lh, Lmsg_w1, Lmsg_b1, T1, N_LITS, DIM, DIM, true);
    gemm(T1, Lmsg_w2, Lmsg_b2, T2, N_LITS, DIM, DIM, true);
    gemm(T2, Lmsg_w3, Lmsg_b3, T1, N_LITS, DIM, DIM, false);
    // X_C = [M^T @ L_pre , Ch];  C gates; C LSTM update
    spmm_cls_kernel<<<N_CLAUSES, 128, 0, stream>>>(cls_ptr, cls_col, T1, Ch, X);
    gemm(X, WC, bC, gates, N_CLAUSES, 512, 256, false);
    lstm_ew_kernel<<<(N_CLAUSES * DIM + 255) / 256, 256, 0, stream>>>(gates, Ch, Cc, N_CLAUSES);
    // C_pre = MLP(Ch)
    gemm(Ch, Cmsg_w1, Cmsg_b1, T1, N_CLAUSES, DIM, DIM, true);
    gemm(T1, Cmsg_w2, Cmsg_b2, T2, N_CLAUSES, DIM, DIM, true);
    gemm(T2, Cmsg_w3, Cmsg_b3, T1, N_CLAUSES, DIM, DIM, false);
    // X_L = [M @ C_pre , Lh(flip) , Lh];  L gates; L LSTM update
    spmm_lit_kernel<<<N_LITS, 128, 0, stream>>>(lit_ptr, lit_col, T1, Lh, X);
    gemm(X, WL, bL, gates, N_LITS, 512, 384, false);
    lstm_ew_kernel<<<(N_LITS * DIM + 255) / 256, 256, 0, stream>>>(gates, Lh, Lc, N_LITS);
  }

  // vote MLP + per-problem mean
  gemm(Lh, Lvote_w1, Lvote_b1, T1, N_LITS, DIM, DIM, true);
  gemm(T1, Lvote_w2, Lvote_b2, T2, N_LITS, DIM, DIM, true);
  vote_kernel<<<N_LITS, 64, 0, stream>>>(T2, Lvote_w3, Lvote_b3, vote);
  prob_mean_kernel<<<N_PROBS, 256, 0, stream>>>(vote, out);
}

// Round 2
// 3524.870 us; speedup vs baseline: 1.1010x; 1.1010x over previous
//
#include <hip/hip_runtime.h>
#include <cstdint>
#include <cstddef>

#define N_VARS   4000
#define N_LITS   8000
#define N_CLAUSES 16000
#define N_CELLS  48000
#define DIM      128
#define N_ROUNDS 16
#define N_PROBS  8

typedef __bf16 bf16x8 __attribute__((ext_vector_type(8)));
typedef float f32x4 __attribute__((ext_vector_type(4)));

__device__ inline unsigned short f2bf(float x) {
  unsigned int u = __float_as_uint(x);
  u += 0x7fffu + ((u >> 16) & 1u);          // RTNE
  return (unsigned short)(u >> 16);
}
__device__ inline float bflo(unsigned int v) { return __uint_as_float(v << 16); }
__device__ inline float bfhi(unsigned int v) { return __uint_as_float(v & 0xffff0000u); }
__device__ inline unsigned int pack2(float a, float b) {
  return (unsigned int)f2bf(a) | ((unsigned int)f2bf(b) << 16);
}
__device__ inline bf16x8 ld_frag(const unsigned short* p) {
  uint4 u = *reinterpret_cast<const uint4*>(p);
  return __builtin_bit_cast(bf16x8, u);
}

// ---------------------------------------------------------------------------
// Fused 3-layer MLP: out = (relu(relu(A@W1^T+b1)@W2^T+b2))@W3^T+b3, all [*,128].
// 256 thr = 4 waves, 64 rows/block, wave owns 16 rows end-to-end (no barriers).
// A,W*,out bf16 (ushort); bias fp32. LDS only for the inter-layer transpose.
// ---------------------------------------------------------------------------
__global__ __launch_bounds__(256) void fused_mlp3(
    const unsigned short* __restrict__ A,
    const unsigned short* __restrict__ W1, const float* __restrict__ b1,
    const unsigned short* __restrict__ W2, const float* __restrict__ b2,
    const unsigned short* __restrict__ W3, const float* __restrict__ b3,
    unsigned short* __restrict__ out) {
  __shared__ __align__(16) unsigned short xbuf[2][4][16][136];
  const int w = threadIdx.x >> 6, l = threadIdx.x & 63;
  const int r = l & 15, kc = l >> 4;
  const int row0 = blockIdx.x * 64 + w * 16;

  f32x4 acc[8];
  // ---- layer 1 (A from global) ----
#pragma unroll
  for (int t = 0; t < 8; ++t) acc[t] = (f32x4){0.f, 0.f, 0.f, 0.f};
#pragma unroll
  for (int ks = 0; ks < 4; ++ks) {
    bf16x8 a = ld_frag(&A[(size_t)(row0 + r) * 128 + ks * 32 + kc * 8]);
#pragma unroll
    for (int t = 0; t < 8; ++t) {
      bf16x8 b = ld_frag(&W1[(size_t)(t * 16 + r) * 128 + ks * 32 + kc * 8]);
      acc[t] = __builtin_amdgcn_mfma_f32_16x16x32_bf16(a, b, acc[t], 0, 0, 0);
    }
  }
#pragma unroll
  for (int t = 0; t < 8; ++t) {
    float bv = b1[t * 16 + r];
#pragma unroll
    for (int j = 0; j < 4; ++j)
      xbuf[0][w][kc * 4 + j][t * 16 + r] = f2bf(fmaxf(acc[t][j] + bv, 0.f));
  }
  // ---- layer 2 (A from LDS) ----
#pragma unroll
  for (int t = 0; t < 8; ++t) acc[t] = (f32x4){0.f, 0.f, 0.f, 0.f};
#pragma unroll
  for (int ks = 0; ks < 4; ++ks) {
    bf16x8 a = ld_frag(&xbuf[0][w][r][ks * 32 + kc * 8]);
#pragma unroll
    for (int t = 0; t < 8; ++t) {
      bf16x8 b = ld_frag(&W2[(size_t)(t * 16 + r) * 128 + ks * 32 + kc * 8]);
      acc[t] = __builtin_amdgcn_mfma_f32_16x16x32_bf16(a, b, acc[t], 0, 0, 0);
    }
  }
#pragma unroll
  for (int t = 0; t < 8; ++t) {
    float bv = b2[t * 16 + r];
#pragma unroll
    for (int j = 0; j < 4; ++j)
      xbuf[1][w][kc * 4 + j][t * 16 + r] = f2bf(fmaxf(acc[t][j] + bv, 0.f));
  }
  // ---- layer 3 (linear) ----
#pragma unroll
  for (int t = 0; t < 8; ++t) acc[t] = (f32x4){0.f, 0.f, 0.f, 0.f};
#pragma unroll
  for (int ks = 0; ks < 4; ++ks) {
    bf16x8 a = ld_frag(&xbuf[1][w][r][ks * 32 + kc * 8]);
#pragma unroll
    for (int t = 0; t < 8; ++t) {
      bf16x8 b = ld_frag(&W3[(size_t)(t * 16 + r) * 128 + ks * 32 + kc * 8]);
      acc[t] = __builtin_amdgcn_mfma_f32_16x16x32_bf16(a, b, acc[t], 0, 0, 0);
    }
  }
#pragma unroll
  for (int t = 0; t < 8; ++t) {
    float bv = b3[t * 16 + r];
#pragma unroll
    for (int j = 0; j < 4; ++j)
      out[(size_t)(row0 + kc * 4 + j) * 128 + t * 16 + r] = f2bf(acc[t][j] + bv);
  }
}

// ---------------------------------------------------------------------------
// Fused vote: relu(relu(A@W1^T+b1)@W2^T+b2) . w3 + b3 -> vote[M] (fp32)
// ---------------------------------------------------------------------------
__global__ __launch_bounds__(256) void fused_vote(
    const unsigned short* __restrict__ A,
    const unsigned short* __restrict__ W1, const float* __restrict__ b1,
    const unsigned short* __restrict__ W2, const float* __restrict__ b2,
    const float* __restrict__ w3, const float* __restrict__ b3,
    float* __restrict__ vote) {
  __shared__ __align__(16) unsigned short xbuf[4][16][136];
  const int w = threadIdx.x >> 6, l = threadIdx.x & 63;
  const int r = l & 15, kc = l >> 4;
  const int row0 = blockIdx.x * 64 + w * 16;

  f32x4 acc[8];
#pragma unroll
  for (int t = 0; t < 8; ++t) acc[t] = (f32x4){0.f, 0.f, 0.f, 0.f};
#pragma unroll
  for (int ks = 0; ks < 4; ++ks) {
    bf16x8 a = ld_frag(&A[(size_t)(row0 + r) * 128 + ks * 32 + kc * 8]);
#pragma unroll
    for (int t = 0; t < 8; ++t) {
      bf16x8 b = ld_frag(&W1[(size_t)(t * 16 + r) * 128 + ks * 32 + kc * 8]);
      acc[t] = __builtin_amdgcn_mfma_f32_16x16x32_bf16(a, b, acc[t], 0, 0, 0);
    }
  }
#pragma unroll
  for (int t = 0; t < 8; ++t) {
    float bv = b1[t * 16 + r];
#pragma unroll
    for (int j = 0; j < 4; ++j)
      xbuf[w][kc * 4 + j][t * 16 + r] = f2bf(fmaxf(acc[t][j] + bv, 0.f));
  }
#pragma unroll
  for (int t = 0; t < 8; ++t) acc[t] = (f32x4){0.f, 0.f, 0.f, 0.f};
#pragma unroll
  for (int ks = 0; ks < 4; ++ks) {
    bf16x8 a = ld_frag(&xbuf[w][r][ks * 32 + kc * 8]);
#pragma unroll
    for (int t = 0; t < 8; ++t) {
      bf16x8 b = ld_frag(&W2[(size_t)(t * 16 + r) * 128 + ks * 32 + kc * 8]);
      acc[t] = __builtin_amdgcn_mfma_f32_16x16x32_bf16(a, b, acc[t], 0, 0, 0);
    }
  }
  float vs[4] = {0.f, 0.f, 0.f, 0.f};
#pragma unroll
  for (int t = 0; t < 8; ++t) {
    float bv = b2[t * 16 + r], wv = w3[t * 16 + r];
#pragma unroll
    for (int j = 0; j < 4; ++j)
      vs[j] += fmaxf(acc[t][j] + bv, 0.f) * wv;
  }
#pragma unroll
  for (int off = 1; off < 16; off <<= 1) {
#pragma unroll
    for (int j = 0; j < 4; ++j) vs[j] += __shfl_xor(vs[j], off, 16);
  }
  if (r == 0) {
#pragma unroll
    for (int j = 0; j < 4; ++j) vote[row0 + kc * 4 + j] = vs[j] + b3[0];
  }
}

// ---------------------------------------------------------------------------
// Gates GEMM [M,512] = X[M,K] @ W[512,K]^T + bias, fused LSTM elementwise.
// 128 thr = 2 waves, 32 rows/block; wave owns 16 rows x all 512 cols so
// i/f/g/o for an element are in the same lane (tiles t, t+8, t+16, t+24).
// c fp32 in/out, h bf16 out.
// ---------------------------------------------------------------------------
template<int KSTEPS>
__global__ __launch_bounds__(128) void gates_lstm(
    const unsigned short* __restrict__ X, const unsigned short* __restrict__ W,
    const float* __restrict__ bias,
    float* __restrict__ c, unsigned short* __restrict__ h) {
  constexpr int K = KSTEPS * 32;
  const int w = threadIdx.x >> 6, l = threadIdx.x & 63;
  const int r = l & 15, kc = l >> 4;
  const int row0 = blockIdx.x * 32 + w * 16;

  f32x4 acc[32];
#pragma unroll
  for (int t = 0; t < 32; ++t) acc[t] = (f32x4){0.f, 0.f, 0.f, 0.f};

#pragma unroll
  for (int ks = 0; ks < KSTEPS; ++ks) {
    bf16x8 a = ld_frag(&X[(size_t)(row0 + r) * K + ks * 32 + kc * 8]);
#pragma unroll
    for (int t = 0; t < 32; ++t) {
      bf16x8 b = ld_frag(&W[(size_t)(t * 16 + r) * K + ks * 32 + kc * 8]);
      acc[t] = __builtin_amdgcn_mfma_f32_16x16x32_bf16(a, b, acc[t], 0, 0, 0);
    }
  }

#pragma unroll
  for (int t = 0; t < 8; ++t) {
    const int d = t * 16 + r;
    const float bi = bias[d], bf_ = bias[d + 128], bg = bias[d + 256], bo = bias[d + 384];
#pragma unroll
    for (int j = 0; j < 4; ++j) {
      const size_t idx = (size_t)(row0 + kc * 4 + j) * 128 + d;
      float ig = acc[t][j] + bi;
      float fg = acc[t + 8][j] + bf_;
      float gg = acc[t + 16][j] + bg;
      float og = acc[t + 24][j] + bo;
      float cp = c[idx];
      float si = 1.f / (1.f + __expf(-ig));
      float sf = 1.f / (1.f + __expf(-fg));
      float so = 1.f / (1.f + __expf(-og));
      float cn = sf * cp + si * tanhf(gg);
      c[idx] = cn;
      h[idx] = f2bf(so * tanhf(cn));
    }
  }
}

// ---------------------------------------------------------------------------
// SpMM + X assembly (bf16 in, fp32 accum, bf16 out). 256 thr = 4 rows x 64
// lanes; each lane owns dim pair (2l, 2l+1) via packed uint loads/stores.
// ---------------------------------------------------------------------------
__global__ void spmm_cls_kernel(const int* __restrict__ ptr, const int* __restrict__ col,
                                const unsigned short* __restrict__ Lpre,
                                const unsigned short* __restrict__ Ch,
                                unsigned short* __restrict__ X) {
  const int row = blockIdx.x * 4 + (threadIdx.x >> 6);
  const int l = threadIdx.x & 63;
  const int b = ptr[row], e = ptr[row + 1];
  float s0 = 0.f, s1 = 0.f;
  for (int j = b; j < e; ++j) {
    unsigned int v = *reinterpret_cast<const unsigned int*>(&Lpre[(size_t)col[j] * 128 + 2 * l]);
    s0 += bflo(v); s1 += bfhi(v);
  }
  unsigned int* Xo = reinterpret_cast<unsigned int*>(&X[(size_t)row * 256]);
  Xo[l] = pack2(s0, s1);
  Xo[64 + l] = *reinterpret_cast<const unsigned int*>(&Ch[(size_t)row * 128 + 2 * l]);
}

__global__ void spmm_lit_kernel(const int* __restrict__ ptr, const int* __restrict__ col,
                                const unsigned short* __restrict__ Cpre,
                                const unsigned short* __restrict__ Lh,
                                unsigned short* __restrict__ X) {
  const int row = blockIdx.x * 4 + (threadIdx.x >> 6);
  const int l = threadIdx.x & 63;
  const int b = ptr[row], e = ptr[row + 1];
  float s0 = 0.f, s1 = 0.f;
  for (int j = b; j < e; ++j) {
    unsigned int v = *reinterpret_cast<const unsigned int*>(&Cpre[(size_t)col[j] * 128 + 2 * l]);
    s0 += bflo(v); s1 += bfhi(v);
  }
  const int flip = (row < N_VARS) ? row + N_VARS : row - N_VARS;
  unsigned int* Xo = reinterpret_cast<unsigned int*>(&X[(size_t)row * 384]);
  Xo[l] = pack2(s0, s1);
  Xo[64 + l] = *reinterpret_cast<const unsigned int*>(&Lh[(size_t)flip * 128 + 2 * l]);
  Xo[128 + l] = *reinterpret_cast<const unsigned int*>(&Lh[(size_t)row * 128 + 2 * l]);
}

// ---------------------------------------------------------------------------
// One-time prep: state init (bf16 h, fp32 c), fp32->bf16 weight convert,
// LSTM weight packing WL[512,384]=[Lu_wih|Lu_whh], WC[512,256]=[Cu_wih|Cu_whh].
// ---------------------------------------------------------------------------
__global__ void init_state_kernel(const float* __restrict__ Lw, const float* __restrict__ Lb,
                                  const float* __restrict__ Cw, const float* __restrict__ Cb,
                                  unsigned short* __restrict__ Lh, float* __restrict__ Lc,
                                  unsigned short* __restrict__ Ch, float* __restrict__ Cc) {
  int idx = blockIdx.x * 256 + threadIdx.x;
  if (idx >= N_CLAUSES * DIM) return;
  int d = idx & 127;
  Ch[idx] = f2bf(Cw[d] + Cb[d]);
  Cc[idx] = 0.f;
  if (idx < N_LITS * DIM) {
    Lh[idx] = f2bf(Lw[d] + Lb[d]);
    Lc[idx] = 0.f;
  }
}

__global__ void cvt_kernel(const float* __restrict__ in, unsigned short* __restrict__ out, int n) {
  int i = blockIdx.x * 256 + threadIdx.x;
  if (i < n) out[i] = f2bf(in[i]);
}

__global__ void pack_lstm_kernel(const float* __restrict__ Lu_wih, const float* __restrict__ Lu_whh,
                                 const float* __restrict__ Lu_bih, const float* __restrict__ Lu_bhh,
                                 const float* __restrict__ Cu_wih, const float* __restrict__ Cu_whh,
                                 const float* __restrict__ Cu_bih, const float* __restrict__ Cu_bhh,
                                 unsigned short* __restrict__ WL, unsigned short* __restrict__ WC,
                                 float* __restrict__ bL, float* __restrict__ bC) {
  int idx = blockIdx.x * 256 + threadIdx.x;
  if (idx < 512 * 384) {
    int n = idx / 384, k = idx % 384;
    WL[idx] = f2bf((k < 256) ? Lu_wih[n * 256 + k] : Lu_whh[n * 128 + (k - 256)]);
  }
  if (idx < 512 * 256) {
    int n = idx / 256, k = idx % 256;
    WC[idx] = f2bf((k < 128) ? Cu_wih[n * 128 + k] : Cu_whh[n * 128 + (k - 128)]);
  }
  if (idx < 512) {
    bL[idx] = Lu_bih[idx] + Lu_bhh[idx];
    bC[idx] = Cu_bih[idx] + Cu_bhh[idx];
  }
}

// ---------------------------------------------------------------------------
// CSR build (unchanged from round 1).
// ---------------------------------------------------------------------------
__global__ void count_kernel(const int* __restrict__ uidx,
                             int* __restrict__ lit_cnt, int* __restrict__ cls_cnt) {
  int i = blockIdx.x * 256 + threadIdx.x;
  if (i < N_CELLS) {
    atomicAdd(&lit_cnt[uidx[2 * i]], 1);
    atomicAdd(&cls_cnt[uidx[2 * i + 1]], 1);
  }
}

__global__ void scan_kernel(const int* __restrict__ cnt, int* __restrict__ ptr, int n) {
  __shared__ int part[1024];
  __shared__ int total;
  int t = threadIdx.x;
  int chunk = (n + 1023) >> 10;
  int lo = t * chunk, hi = min(lo + chunk, n);
  int s = 0;
  for (int i = lo; i < hi; ++i) s += cnt[i];
  part[t] = s;
  __syncthreads();
  if (t == 0) {
    int acc = 0;
    for (int i = 0; i < 1024; ++i) { int v = part[i]; part[i] = acc; acc += v; }
    total = acc;
  }
  __syncthreads();
  int acc = part[t];
  for (int i = lo; i < hi; ++i) { ptr[i] = acc; acc += cnt[i]; }
  if (t == 0) ptr[n] = total;
}

__global__ void scatter_kernel(const int* __restrict__ uidx,
                               const int* __restrict__ lit_ptr, const int* __restrict__ cls_ptr,
                               int* __restrict__ lit_fill, int* __restrict__ cls_fill,
                               int* __restrict__ lit_col, int* __restrict__ cls_col) {
  int i = blockIdx.x * 256 + threadIdx.x;
  if (i < N_CELLS) {
    int lit = uidx[2 * i], cls = uidx[2 * i + 1];
    int p = atomicAdd(&lit_fill[lit], 1);
    lit_col[lit_ptr[lit] + p] = cls;
    int q = atomicAdd(&cls_fill[cls], 1);
    cls_col[cls_ptr[cls] + q] = lit;
  }
}

__global__ void prob_mean_kernel(const float* __restrict__ vote, float* __restrict__ out) {
  int p = blockIdx.x;
  int t = threadIdx.x;
  float s = 0.f;
  for (int i = t; i < 500; i += 256) s += vote[p * 500 + i] + vote[N_VARS + p * 500 + i];
  __shared__ float red[256];
  red[t] = s;
  __syncthreads();
  for (int off = 128; off > 0; off >>= 1) {
    if (t < off) red[t] += red[t + off];
    __syncthreads();
  }
  if (t == 0) out[p] = red[0] * (1.0f / 1000.0f);
}

// ---------------------------------------------------------------------------
extern "C" void kernel_launch(void* const* d_in, const int* in_sizes, int n_in,
                              void* d_out, int out_size, void* d_ws, size_t ws_size,
                              hipStream_t stream) {
  (void)in_sizes; (void)n_in; (void)out_size;
  const int* uidx = (const int*)d_in[0];
  const float* L_init_w = (const float*)d_in[4];
  const float* L_init_b = (const float*)d_in[5];
  const float* C_init_w = (const float*)d_in[6];
  const float* C_init_b = (const float*)d_in[7];
  const float* Lmsg_w1 = (const float*)d_in[8],  *Lmsg_b1 = (const float*)d_in[9];
  const float* Lmsg_w2 = (const float*)d_in[10], *Lmsg_b2 = (const float*)d_in[11];
  const float* Lmsg_w3 = (const float*)d_in[12], *Lmsg_b3 = (const float*)d_in[13];
  const float* Cmsg_w1 = (const float*)d_in[14], *Cmsg_b1 = (const float*)d_in[15];
  const float* Cmsg_w2 = (const float*)d_in[16], *Cmsg_b2 = (const float*)d_in[17];
  const float* Cmsg_w3 = (const float*)d_in[18], *Cmsg_b3 = (const float*)d_in[19];
  const float* Lvote_w1 = (const float*)d_in[20], *Lvote_b1 = (const float*)d_in[21];
  const float* Lvote_w2 = (const float*)d_in[22], *Lvote_b2 = (const float*)d_in[23];
  const float* Lvote_w3 = (const float*)d_in[24], *Lvote_b3 = (const float*)d_in[25];
  const float* Lu_wih = (const float*)d_in[26], *Lu_whh = (const float*)d_in[27];
  const float* Lu_bih = (const float*)d_in[28], *Lu_bhh = (const float*)d_in[29];
  const float* Cu_wih = (const float*)d_in[30], *Cu_whh = (const float*)d_in[31];
  const float* Cu_bih = (const float*)d_in[32], *Cu_bhh = (const float*)d_in[33];
  float* out = (float*)d_out;

  // ---- workspace carve-up (256B-aligned byte allocator) ----
  char* base = (char*)d_ws;
  size_t off = 0;
  auto alloc = [&](size_t bytes) {
    void* p = base + off;
    off = (off + bytes + 255) & ~(size_t)255;
    return p;
  };
  float* Lc   = (float*)alloc((size_t)N_LITS * DIM * 4);
  float* Cc   = (float*)alloc((size_t)N_CLAUSES * DIM * 4);
  float* bL   = (float*)alloc(512 * 4);
  float* bC   = (float*)alloc(512 * 4);
  float* vote = (float*)alloc(N_LITS * 4);
  unsigned short* Lh  = (unsigned short*)alloc((size_t)N_LITS * DIM * 2);
  unsigned short* Ch  = (unsigned short*)alloc((size_t)N_CLAUSES * DIM * 2);
  unsigned short* T   = (unsigned short*)alloc((size_t)N_CLAUSES * DIM * 2);
  unsigned short* X   = (unsigned short*)alloc((size_t)N_CLAUSES * 256 * 2);
  unsigned short* WLp = (unsigned short*)alloc(512 * 384 * 2);
  unsigned short* WCp = (unsigned short*)alloc(512 * 256 * 2);
  unsigned short* wLm1 = (unsigned short*)alloc(DIM * DIM * 2);
  unsigned short* wLm2 = (unsigned short*)alloc(DIM * DIM * 2);
  unsigned short* wLm3 = (unsigned short*)alloc(DIM * DIM * 2);
  unsigned short* wCm1 = (unsigned short*)alloc(DIM * DIM * 2);
  unsigned short* wCm2 = (unsigned short*)alloc(DIM * DIM * 2);
  unsigned short* wCm3 = (unsigned short*)alloc(DIM * DIM * 2);
  unsigned short* wV1  = (unsigned short*)alloc(DIM * DIM * 2);
  unsigned short* wV2  = (unsigned short*)alloc(DIM * DIM * 2);
  int* lit_cnt  = (int*)alloc(N_LITS * 4);
  int* cls_cnt  = (int*)alloc(N_CLAUSES * 4);
  int* lit_fill = (int*)alloc(N_LITS * 4);
  int* cls_fill = (int*)alloc(N_CLAUSES * 4);
  int* lit_ptr  = (int*)alloc((N_LITS + 1) * 4);
  int* cls_ptr  = (int*)alloc((N_CLAUSES + 1) * 4);
  int* lit_col  = (int*)alloc(N_CELLS * 4);
  int* cls_col  = (int*)alloc(N_CELLS * 4);
  if (off > ws_size) return;

  // ---- CSR build (redone every launch: ws is not re-poisoned) ----
  hipMemsetAsync(lit_cnt, 0, (char*)lit_ptr - (char*)lit_cnt, stream);
  count_kernel<<<(N_CELLS + 255) / 256, 256, 0, stream>>>(uidx, lit_cnt, cls_cnt);
  scan_kernel<<<1, 1024, 0, stream>>>(lit_cnt, lit_ptr, N_LITS);
  scan_kernel<<<1, 1024, 0, stream>>>(cls_cnt, cls_ptr, N_CLAUSES);
  scatter_kernel<<<(N_CELLS + 255) / 256, 256, 0, stream>>>(
      uidx, lit_ptr, cls_ptr, lit_fill, cls_fill, lit_col, cls_col);

  // ---- one-time weight conversion / packing / state init ----
  init_state_kernel<<<(N_CLAUSES * DIM + 255) / 256, 256, 0, stream>>>(
      L_init_w, L_init_b, C_init_w, C_init_b, Lh, Lc, Ch, Cc);
  pack_lstm_kernel<<<(512 * 384 + 255) / 256, 256, 0, stream>>>(
      Lu_wih, Lu_whh, Lu_bih, Lu_bhh, Cu_wih, Cu_whh, Cu_bih, Cu_bhh, WLp, WCp, bL, bC);
  const int NW = DIM * DIM;
  cvt_kernel<<<NW / 256, 256, 0, stream>>>(Lmsg_w1, wLm1, NW);
  cvt_kernel<<<NW / 256, 256, 0, stream>>>(Lmsg_w2, wLm2, NW);
  cvt_kernel<<<NW / 256, 256, 0, stream>>>(Lmsg_w3, wLm3, NW);
  cvt_kernel<<<NW / 256, 256, 0, stream>>>(Cmsg_w1, wCm1, NW);
  cvt_kernel<<<NW / 256, 256, 0, stream>>>(Cmsg_w2, wCm2, NW);
  cvt_kernel<<<NW / 256, 256, 0, stream>>>(Cmsg_w3, wCm3, NW);
  cvt_kernel<<<NW / 256, 256, 0, stream>>>(Lvote_w1, wV1, NW);
  cvt_kernel<<<NW / 256, 256, 0, stream>>>(Lvote_w2, wV2, NW);

  // ---- message-passing rounds ----
  for (int r = 0; r < N_ROUNDS; ++r) {
    fused_mlp3<<<N_LITS / 64, 256, 0, stream>>>(
        Lh, wLm1, Lmsg_b1, wLm2, Lmsg_b2, wLm3, Lmsg_b3, T);
    spmm_cls_kernel<<<N_CLAUSES / 4, 256, 0, stream>>>(cls_ptr, cls_col, T, Ch, X);
    gates_lstm<8><<<N_CLAUSES / 32, 128, 0, stream>>>(X, WCp, bC, Cc, Ch);
    fused_mlp3<<<N_CLAUSES / 64, 256, 0, stream>>>(
        Ch, wCm1, Cmsg_b1, wCm2, Cmsg_b2, wCm3, Cmsg_b3, T);
    spmm_lit_kernel<<<N_LITS / 4, 256, 0, stream>>>(lit_ptr, lit_col, T, Lh, X);
    gates_lstm<12><<<N_LITS / 32, 128, 0, stream>>>(X, WLp, bL, Lc, Lh);
  }

  // ---- vote + per-problem mean ----
  fused_vote<<<N_LITS / 64, 256, 0, stream>>>(
      Lh, wV1, Lvote_b1, wV2, Lvote_b2, Lvote_w3, Lvote_b3, vote);
  prob_mean_kernel<<<N_PROBS, 256, 0, stream>>>(vote, out);
}

// Round 3
// 1637.320 us; speedup vs baseline: 2.3702x; 2.1528x over previous
//
#include <hip/hip_runtime.h>
#include <cstdint>
#include <cstddef>

#define N_VARS   4000
#define N_LITS   8000
#define N_CLAUSES 16000
#define N_CELLS  48000
#define DIM      128
#define N_ROUNDS 16
#define N_PROBS  8

typedef __bf16 bf16x8 __attribute__((ext_vector_type(8)));
typedef float f32x4 __attribute__((ext_vector_type(4)));

__device__ inline unsigned short f2bf(float x) {
  unsigned int u = __float_as_uint(x);
  u += 0x7fffu + ((u >> 16) & 1u);          // RTNE
  return (unsigned short)(u >> 16);
}
__device__ inline float bflo(unsigned int v) { return __uint_as_float(v << 16); }
__device__ inline float bfhi(unsigned int v) { return __uint_as_float(v & 0xffff0000u); }
__device__ inline unsigned int pack2(float a, float b) {
  return (unsigned int)f2bf(a) | ((unsigned int)f2bf(b) << 16);
}
__device__ inline bf16x8 ld_frag(const unsigned short* p) {
  uint4 u = *reinterpret_cast<const uint4*>(p);
  return __builtin_bit_cast(bf16x8, u);
}
__device__ inline float fast_sigmoid(float x) { return 1.f / (1.f + __expf(-x)); }
__device__ inline float fast_tanh(float x) {
  float t = __expf(-2.f * x);
  return (1.f - t) / (1.f + t);
}

// ---------------------------------------------------------------------------
// Fused 3-layer MLP, single-wave blocks (64 thr), 16 rows per block.
// out = relu(relu(A@W1^T+b1)@W2^T+b2)@W3^T+b3, all [*,128] bf16.
// ---------------------------------------------------------------------------
__global__ __launch_bounds__(64) void fused_mlp3(
    const unsigned short* __restrict__ A,
    const unsigned short* __restrict__ W1, const float* __restrict__ b1,
    const unsigned short* __restrict__ W2, const float* __restrict__ b2,
    const unsigned short* __restrict__ W3, const float* __restrict__ b3,
    unsigned short* __restrict__ out) {
  __shared__ __align__(16) unsigned short xb[16][136];   // 272B pitch, 16B aligned
  const int l = threadIdx.x;
  const int r = l & 15, kc = l >> 4;
  const int row0 = blockIdx.x * 16;

  f32x4 acc[8];
  // ---- layer 1 (A from global) ----
#pragma unroll
  for (int t = 0; t < 8; ++t) acc[t] = (f32x4){0.f, 0.f, 0.f, 0.f};
#pragma unroll
  for (int ks = 0; ks < 4; ++ks) {
    bf16x8 a = ld_frag(&A[(size_t)(row0 + r) * 128 + ks * 32 + kc * 8]);
#pragma unroll
    for (int t = 0; t < 8; ++t) {
      bf16x8 b = ld_frag(&W1[(size_t)(t * 16 + r) * 128 + ks * 32 + kc * 8]);
      acc[t] = __builtin_amdgcn_mfma_f32_16x16x32_bf16(a, b, acc[t], 0, 0, 0);
    }
  }
#pragma unroll
  for (int t = 0; t < 8; ++t) {
    float bv = b1[t * 16 + r];
#pragma unroll
    for (int j = 0; j < 4; ++j)
      xb[kc * 4 + j][t * 16 + r] = f2bf(fmaxf(acc[t][j] + bv, 0.f));
  }
  __syncthreads();
  // ---- layer 2 (A from LDS) ----
#pragma unroll
  for (int t = 0; t < 8; ++t) acc[t] = (f32x4){0.f, 0.f, 0.f, 0.f};
#pragma unroll
  for (int ks = 0; ks < 4; ++ks) {
    bf16x8 a = ld_frag(&xb[r][ks * 32 + kc * 8]);
#pragma unroll
    for (int t = 0; t < 8; ++t) {
      bf16x8 b = ld_frag(&W2[(size_t)(t * 16 + r) * 128 + ks * 32 + kc * 8]);
      acc[t] = __builtin_amdgcn_mfma_f32_16x16x32_bf16(a, b, acc[t], 0, 0, 0);
    }
  }
  __syncthreads();
#pragma unroll
  for (int t = 0; t < 8; ++t) {
    float bv = b2[t * 16 + r];
#pragma unroll
    for (int j = 0; j < 4; ++j)
      xb[kc * 4 + j][t * 16 + r] = f2bf(fmaxf(acc[t][j] + bv, 0.f));
  }
  __syncthreads();
  // ---- layer 3 (linear) ----
#pragma unroll
  for (int t = 0; t < 8; ++t) acc[t] = (f32x4){0.f, 0.f, 0.f, 0.f};
#pragma unroll
  for (int ks = 0; ks < 4; ++ks) {
    bf16x8 a = ld_frag(&xb[r][ks * 32 + kc * 8]);
#pragma unroll
    for (int t = 0; t < 8; ++t) {
      bf16x8 b = ld_frag(&W3[(size_t)(t * 16 + r) * 128 + ks * 32 + kc * 8]);
      acc[t] = __builtin_amdgcn_mfma_f32_16x16x32_bf16(a, b, acc[t], 0, 0, 0);
    }
  }
#pragma unroll
  for (int t = 0; t < 8; ++t) {
    float bv = b3[t * 16 + r];
#pragma unroll
    for (int j = 0; j < 4; ++j)
      out[(size_t)(row0 + kc * 4 + j) * 128 + t * 16 + r] = f2bf(acc[t][j] + bv);
  }
}

// ---------------------------------------------------------------------------
// Fused vote: relu(relu(A@W1^T+b1)@W2^T+b2) . w3 + b3 -> vote[M] (fp32)
// ---------------------------------------------------------------------------
__global__ __launch_bounds__(256) void fused_vote(
    const unsigned short* __restrict__ A,
    const unsigned short* __restrict__ W1, const float* __restrict__ b1,
    const unsigned short* __restrict__ W2, const float* __restrict__ b2,
    const float* __restrict__ w3, const float* __restrict__ b3,
    float* __restrict__ vote) {
  __shared__ __align__(16) unsigned short xbuf[4][16][136];
  const int w = threadIdx.x >> 6, l = threadIdx.x & 63;
  const int r = l & 15, kc = l >> 4;
  const int row0 = blockIdx.x * 64 + w * 16;

  f32x4 acc[8];
#pragma unroll
  for (int t = 0; t < 8; ++t) acc[t] = (f32x4){0.f, 0.f, 0.f, 0.f};
#pragma unroll
  for (int ks = 0; ks < 4; ++ks) {
    bf16x8 a = ld_frag(&A[(size_t)(row0 + r) * 128 + ks * 32 + kc * 8]);
#pragma unroll
    for (int t = 0; t < 8; ++t) {
      bf16x8 b = ld_frag(&W1[(size_t)(t * 16 + r) * 128 + ks * 32 + kc * 8]);
      acc[t] = __builtin_amdgcn_mfma_f32_16x16x32_bf16(a, b, acc[t], 0, 0, 0);
    }
  }
#pragma unroll
  for (int t = 0; t < 8; ++t) {
    float bv = b1[t * 16 + r];
#pragma unroll
    for (int j = 0; j < 4; ++j)
      xbuf[w][kc * 4 + j][t * 16 + r] = f2bf(fmaxf(acc[t][j] + bv, 0.f));
  }
#pragma unroll
  for (int t = 0; t < 8; ++t) acc[t] = (f32x4){0.f, 0.f, 0.f, 0.f};
#pragma unroll
  for (int ks = 0; ks < 4; ++ks) {
    bf16x8 a = ld_frag(&xbuf[w][r][ks * 32 + kc * 8]);
#pragma unroll
    for (int t = 0; t < 8; ++t) {
      bf16x8 b = ld_frag(&W2[(size_t)(t * 16 + r) * 128 + ks * 32 + kc * 8]);
      acc[t] = __builtin_amdgcn_mfma_f32_16x16x32_bf16(a, b, acc[t], 0, 0, 0);
    }
  }
  float vs[4] = {0.f, 0.f, 0.f, 0.f};
#pragma unroll
  for (int t = 0; t < 8; ++t) {
    float bv = b2[t * 16 + r], wv = w3[t * 16 + r];
#pragma unroll
    for (int j = 0; j < 4; ++j)
      vs[j] += fmaxf(acc[t][j] + bv, 0.f) * wv;
  }
#pragma unroll
  for (int off = 1; off < 16; off <<= 1) {
#pragma unroll
    for (int j = 0; j < 4; ++j) vs[j] += __shfl_xor(vs[j], off, 16);
  }
  if (r == 0) {
#pragma unroll
    for (int j = 0; j < 4; ++j) vote[row0 + kc * 4 + j] = vs[j] + b3[0];
  }
}

// ---------------------------------------------------------------------------
// Gates GEMM + fused LSTM, zero-shuffle epilogue.
// mfma(A=W', B=X): C row-dim (regs) indexes W' rows. W' row permutation:
//   n' = w*128 + tt*16 + kc*4 + j  <->  gate=j, dim d = w*32 + kc*8 + tt
// so lane (r,kc) of wave w holds i,f,g,o of (X-row row0+rg*16+r, dim d) in
// acc[rg][tt][0..3]. Dims per lane are contiguous (kc*8+tt) -> coalesced c/h.
// Block: 4 waves x 128 cols', 32 rows. c fp32, h bf16.
// ---------------------------------------------------------------------------
template<int KSTEPS>
__global__ __launch_bounds__(256) void gates_lstm(
    const unsigned short* __restrict__ X, const unsigned short* __restrict__ Wp,
    const float* __restrict__ biasP,
    float* __restrict__ c, unsigned short* __restrict__ h) {
  constexpr int K = KSTEPS * 32;
  const int w = threadIdx.x >> 6, l = threadIdx.x & 63;
  const int r = l & 15, kc = l >> 4;
  const int row0 = blockIdx.x * 32;

  f32x4 acc[2][8];
#pragma unroll
  for (int rg = 0; rg < 2; ++rg)
#pragma unroll
    for (int t = 0; t < 8; ++t) acc[rg][t] = (f32x4){0.f, 0.f, 0.f, 0.f};

#pragma unroll
  for (int ks = 0; ks < KSTEPS; ++ks) {
    bf16x8 b0 = ld_frag(&X[(size_t)(row0 + r) * K + ks * 32 + kc * 8]);
    bf16x8 b1 = ld_frag(&X[(size_t)(row0 + 16 + r) * K + ks * 32 + kc * 8]);
#pragma unroll
    for (int tt = 0; tt < 8; ++tt) {
      bf16x8 a = ld_frag(&Wp[(size_t)(w * 128 + tt * 16 + r) * K + ks * 32 + kc * 8]);
      acc[0][tt] = __builtin_amdgcn_mfma_f32_16x16x32_bf16(a, b0, acc[0][tt], 0, 0, 0);
      acc[1][tt] = __builtin_amdgcn_mfma_f32_16x16x32_bf16(a, b1, acc[1][tt], 0, 0, 0);
    }
  }

#pragma unroll
  for (int rg = 0; rg < 2; ++rg) {
    const int row = row0 + rg * 16 + r;
    const size_t cbase = (size_t)row * 128 + w * 32 + kc * 8;
    f32x4 c0 = *reinterpret_cast<const f32x4*>(&c[cbase]);
    f32x4 c1 = *reinterpret_cast<const f32x4*>(&c[cbase + 4]);
    f32x4 n0, n1;
    unsigned int hp[4];
#pragma unroll
    for (int tt = 0; tt < 8; ++tt) {
      const float4 bb = *reinterpret_cast<const float4*>(&biasP[w * 128 + tt * 16 + kc * 4]);
      float ig = acc[rg][tt][0] + bb.x;
      float fg = acc[rg][tt][1] + bb.y;
      float gg = acc[rg][tt][2] + bb.z;
      float og = acc[rg][tt][3] + bb.w;
      float cp = (tt < 4) ? c0[tt] : c1[tt - 4];
      float cn = fast_sigmoid(fg) * cp + fast_sigmoid(ig) * fast_tanh(gg);
      float hv = fast_sigmoid(og) * fast_tanh(cn);
      if (tt < 4) n0[tt] = cn; else n1[tt - 4] = cn;
      if (tt & 1) hp[tt >> 1] |= (unsigned int)f2bf(hv) << 16;
      else        hp[tt >> 1]  = (unsigned int)f2bf(hv);
    }
    *reinterpret_cast<f32x4*>(&c[cbase]) = n0;
    *reinterpret_cast<f32x4*>(&c[cbase + 4]) = n1;
    uint4 hv4 = {hp[0], hp[1], hp[2], hp[3]};
    *reinterpret_cast<uint4*>(&h[cbase]) = hv4;
  }
}

// ---------------------------------------------------------------------------
// SpMM + X assembly (bf16 in, fp32 accum, bf16 out).
// ---------------------------------------------------------------------------
__global__ void spmm_cls_kernel(const int* __restrict__ ptr, const int* __restrict__ col,
                                const unsigned short* __restrict__ Lpre,
                                const unsigned short* __restrict__ Ch,
                                unsigned short* __restrict__ X) {
  const int row = blockIdx.x * 4 + (threadIdx.x >> 6);
  const int l = threadIdx.x & 63;
  const int b = ptr[row], e = ptr[row + 1];
  float s0 = 0.f, s1 = 0.f;
  for (int j = b; j < e; ++j) {
    unsigned int v = *reinterpret_cast<const unsigned int*>(&Lpre[(size_t)col[j] * 128 + 2 * l]);
    s0 += bflo(v); s1 += bfhi(v);
  }
  unsigned int* Xo = reinterpret_cast<unsigned int*>(&X[(size_t)row * 256]);
  Xo[l] = pack2(s0, s1);
  Xo[64 + l] = *reinterpret_cast<const unsigned int*>(&Ch[(size_t)row * 128 + 2 * l]);
}

__global__ void spmm_lit_kernel(const int* __restrict__ ptr, const int* __restrict__ col,
                                const unsigned short* __restrict__ Cpre,
                                const unsigned short* __restrict__ Lh,
                                unsigned short* __restrict__ X) {
  const int row = blockIdx.x * 4 + (threadIdx.x >> 6);
  const int l = threadIdx.x & 63;
  const int b = ptr[row], e = ptr[row + 1];
  float s0 = 0.f, s1 = 0.f;
  for (int j = b; j < e; ++j) {
    unsigned int v = *reinterpret_cast<const unsigned int*>(&Cpre[(size_t)col[j] * 128 + 2 * l]);
    s0 += bflo(v); s1 += bfhi(v);
  }
  const int flip = (row < N_VARS) ? row + N_VARS : row - N_VARS;
  unsigned int* Xo = reinterpret_cast<unsigned int*>(&X[(size_t)row * 384]);
  Xo[l] = pack2(s0, s1);
  Xo[64 + l] = *reinterpret_cast<const unsigned int*>(&Lh[(size_t)flip * 128 + 2 * l]);
  Xo[128 + l] = *reinterpret_cast<const unsigned int*>(&Lh[(size_t)row * 128 + 2 * l]);
}

// ---------------------------------------------------------------------------
// One-time prep.
// ---------------------------------------------------------------------------
__global__ void init_state_kernel(const float* __restrict__ Lw, const float* __restrict__ Lb,
                                  const float* __restrict__ Cw, const float* __restrict__ Cb,
                                  unsigned short* __restrict__ Lh, float* __restrict__ Lc,
                                  unsigned short* __restrict__ Ch, float* __restrict__ Cc) {
  int idx = blockIdx.x * 256 + threadIdx.x;
  if (idx >= N_CLAUSES * DIM) return;
  int d = idx & 127;
  Ch[idx] = f2bf(Cw[d] + Cb[d]);
  Cc[idx] = 0.f;
  if (idx < N_LITS * DIM) {
    Lh[idx] = f2bf(Lw[d] + Lb[d]);
    Lc[idx] = 0.f;
  }
}

__global__ void cvt_kernel(const float* __restrict__ in, unsigned short* __restrict__ out, int n) {
  int i = blockIdx.x * 256 + threadIdx.x;
  if (i < n) out[i] = f2bf(in[i]);
}

// W' pack with gate-interleaved row permutation (see gates_lstm comment).
// n' -> orig row: gt = n'&3, d = (n'>>7)*32 + ((n'>>2)&3)*8 + ((n'>>4)&7).
template<int KIH>
__global__ void pack_gates_kernel(const float* __restrict__ wih, const float* __restrict__ whh,
                                  const float* __restrict__ bih, const float* __restrict__ bhh,
                                  unsigned short* __restrict__ Wp, float* __restrict__ bP) {
  constexpr int K = KIH + 128;
  int idx = blockIdx.x * 256 + threadIdx.x;
  if (idx >= 512 * K) return;
  int np = idx / K, k = idx % K;
  int gt = np & 3;
  int d = ((np >> 7) << 5) + (((np >> 2) & 3) << 3) + ((np >> 4) & 7);
  int orig = gt * 128 + d;
  float v = (k < KIH) ? wih[(size_t)orig * KIH + k] : whh[(size_t)orig * 128 + (k - KIH)];
  Wp[idx] = f2bf(v);
  if (k == 0) bP[np] = bih[orig] + bhh[orig];
}

// ---------------------------------------------------------------------------
// CSR build.
// ---------------------------------------------------------------------------
__global__ void count_kernel(const int* __restrict__ uidx,
                             int* __restrict__ lit_cnt, int* __restrict__ cls_cnt) {
  int i = blockIdx.x * 256 + threadIdx.x;
  if (i < N_CELLS) {
    atomicAdd(&lit_cnt[uidx[2 * i]], 1);
    atomicAdd(&cls_cnt[uidx[2 * i + 1]], 1);
  }
}

__global__ void scan_kernel(const int* __restrict__ cnt, int* __restrict__ ptr, int n) {
  __shared__ int part[1024];
  __shared__ int total;
  int t = threadIdx.x;
  int chunk = (n + 1023) >> 10;
  int lo = t * chunk, hi = min(lo + chunk, n);
  int s = 0;
  for (int i = lo; i < hi; ++i) s += cnt[i];
  part[t] = s;
  __syncthreads();
  if (t == 0) {
    int acc = 0;
    for (int i = 0; i < 1024; ++i) { int v = part[i]; part[i] = acc; acc += v; }
    total = acc;
  }
  __syncthreads();
  int acc = part[t];
  for (int i = lo; i < hi; ++i) { ptr[i] = acc; acc += cnt[i]; }
  if (t == 0) ptr[n] = total;
}

__global__ void scatter_kernel(const int* __restrict__ uidx,
                               const int* __restrict__ lit_ptr, const int* __restrict__ cls_ptr,
                               int* __restrict__ lit_fill, int* __restrict__ cls_fill,
                               int* __restrict__ lit_col, int* __restrict__ cls_col) {
  int i = blockIdx.x * 256 + threadIdx.x;
  if (i < N_CELLS) {
    int lit = uidx[2 * i], cls = uidx[2 * i + 1];
    int p = atomicAdd(&lit_fill[lit], 1);
    lit_col[lit_ptr[lit] + p] = cls;
    int q = atomicAdd(&cls_fill[cls], 1);
    cls_col[cls_ptr[cls] + q] = lit;
  }
}

__global__ void prob_mean_kernel(const float* __restrict__ vote, float* __restrict__ out) {
  int p = blockIdx.x;
  int t = threadIdx.x;
  float s = 0.f;
  for (int i = t; i < 500; i += 256) s += vote[p * 500 + i] + vote[N_VARS + p * 500 + i];
  __shared__ float red[256];
  red[t] = s;
  __syncthreads();
  for (int off = 128; off > 0; off >>= 1) {
    if (t < off) red[t] += red[t + off];
    __syncthreads();
  }
  if (t == 0) out[p] = red[0] * (1.0f / 1000.0f);
}

// ---------------------------------------------------------------------------
extern "C" void kernel_launch(void* const* d_in, const int* in_sizes, int n_in,
                              void* d_out, int out_size, void* d_ws, size_t ws_size,
                              hipStream_t stream) {
  (void)in_sizes; (void)n_in; (void)out_size;
  const int* uidx = (const int*)d_in[0];
  const float* L_init_w = (const float*)d_in[4];
  const float* L_init_b = (const float*)d_in[5];
  const float* C_init_w = (const float*)d_in[6];
  const float* C_init_b = (const float*)d_in[7];
  const float* Lmsg_w1 = (const float*)d_in[8],  *Lmsg_b1 = (const float*)d_in[9];
  const float* Lmsg_w2 = (const float*)d_in[10], *Lmsg_b2 = (const float*)d_in[11];
  const float* Lmsg_w3 = (const float*)d_in[12], *Lmsg_b3 = (const float*)d_in[13];
  const float* Cmsg_w1 = (const float*)d_in[14], *Cmsg_b1 = (const float*)d_in[15];
  const float* Cmsg_w2 = (const float*)d_in[16], *Cmsg_b2 = (const float*)d_in[17];
  const float* Cmsg_w3 = (const float*)d_in[18], *Cmsg_b3 = (const float*)d_in[19];
  const float* Lvote_w1 = (const float*)d_in[20], *Lvote_b1 = (const float*)d_in[21];
  const float* Lvote_w2 = (const float*)d_in[22], *Lvote_b2 = (const float*)d_in[23];
  const float* Lvote_w3 = (const float*)d_in[24], *Lvote_b3 = (const float*)d_in[25];
  const float* Lu_wih = (const float*)d_in[26], *Lu_whh = (const float*)d_in[27];
  const float* Lu_bih = (const float*)d_in[28], *Lu_bhh = (const float*)d_in[29];
  const float* Cu_wih = (const float*)d_in[30], *Cu_whh = (const float*)d_in[31];
  const float* Cu_bih = (const float*)d_in[32], *Cu_bhh = (const float*)d_in[33];
  float* out = (float*)d_out;

  // ---- workspace carve-up ----
  char* base = (char*)d_ws;
  size_t off = 0;
  auto alloc = [&](size_t bytes) {
    void* p = base + off;
    off = (off + bytes + 255) & ~(size_t)255;
    return p;
  };
  float* Lc   = (float*)alloc((size_t)N_LITS * DIM * 4);
  float* Cc   = (float*)alloc((size_t)N_CLAUSES * DIM * 4);
  float* bL   = (float*)alloc(512 * 4);
  float* bC   = (float*)alloc(512 * 4);
  float* vote = (float*)alloc(N_LITS * 4);
  unsigned short* Lh  = (unsigned short*)alloc((size_t)N_LITS * DIM * 2);
  unsigned short* Ch  = (unsigned short*)alloc((size_t)N_CLAUSES * DIM * 2);
  unsigned short* T   = (unsigned short*)alloc((size_t)N_CLAUSES * DIM * 2);
  unsigned short* X   = (unsigned short*)alloc((size_t)N_CLAUSES * 256 * 2);
  unsigned short* WLp = (unsigned short*)alloc(512 * 384 * 2);
  unsigned short* WCp = (unsigned short*)alloc(512 * 256 * 2);
  unsigned short* wLm1 = (unsigned short*)alloc(DIM * DIM * 2);
  unsigned short* wLm2 = (unsigned short*)alloc(DIM * DIM * 2);
  unsigned short* wLm3 = (unsigned short*)alloc(DIM * DIM * 2);
  unsigned short* wCm1 = (unsigned short*)alloc(DIM * DIM * 2);
  unsigned short* wCm2 = (unsigned short*)alloc(DIM * DIM * 2);
  unsigned short* wCm3 = (unsigned short*)alloc(DIM * DIM * 2);
  unsigned short* wV1  = (unsigned short*)alloc(DIM * DIM * 2);
  unsigned short* wV2  = (unsigned short*)alloc(DIM * DIM * 2);
  int* lit_cnt  = (int*)alloc(N_LITS * 4);
  int* cls_cnt  = (int*)alloc(N_CLAUSES * 4);
  int* lit_fill = (int*)alloc(N_LITS * 4);
  int* cls_fill = (int*)alloc(N_CLAUSES * 4);
  int* lit_ptr  = (int*)alloc((N_LITS + 1) * 4);
  int* cls_ptr  = (int*)alloc((N_CLAUSES + 1) * 4);
  int* lit_col  = (int*)alloc(N_CELLS * 4);
  int* cls_col  = (int*)alloc(N_CELLS * 4);
  if (off > ws_size) return;

  // ---- CSR build (redone every launch) ----
  hipMemsetAsync(lit_cnt, 0, (char*)lit_ptr - (char*)lit_cnt, stream);
  count_kernel<<<(N_CELLS + 255) / 256, 256, 0, stream>>>(uidx, lit_cnt, cls_cnt);
  scan_kernel<<<1, 1024, 0, stream>>>(lit_cnt, lit_ptr, N_LITS);
  scan_kernel<<<1, 1024, 0, stream>>>(cls_cnt, cls_ptr, N_CLAUSES);
  scatter_kernel<<<(N_CELLS + 255) / 256, 256, 0, stream>>>(
      uidx, lit_ptr, cls_ptr, lit_fill, cls_fill, lit_col, cls_col);

  // ---- one-time weight conversion / packing / state init ----
  init_state_kernel<<<(N_CLAUSES * DIM + 255) / 256, 256, 0, stream>>>(
      L_init_w, L_init_b, C_init_w, C_init_b, Lh, Lc, Ch, Cc);
  pack_gates_kernel<256><<<(512 * 384 + 255) / 256, 256, 0, stream>>>(
      Lu_wih, Lu_whh, Lu_bih, Lu_bhh, WLp, bL);
  pack_gates_kernel<128><<<(512 * 256 + 255) / 256, 256, 0, stream>>>(
      Cu_wih, Cu_whh, Cu_bih, Cu_bhh, WCp, bC);
  const int NW = DIM * DIM;
  cvt_kernel<<<NW / 256, 256, 0, stream>>>(Lmsg_w1, wLm1, NW);
  cvt_kernel<<<NW / 256, 256, 0, stream>>>(Lmsg_w2, wLm2, NW);
  cvt_kernel<<<NW / 256, 256, 0, stream>>>(Lmsg_w3, wLm3, NW);
  cvt_kernel<<<NW / 256, 256, 0, stream>>>(Cmsg_w1, wCm1, NW);
  cvt_kernel<<<NW / 256, 256, 0, stream>>>(Cmsg_w2, wCm2, NW);
  cvt_kernel<<<NW / 256, 256, 0, stream>>>(Cmsg_w3, wCm3, NW);
  cvt_kernel<<<NW / 256, 256, 0, stream>>>(Lvote_w1, wV1, NW);
  cvt_kernel<<<NW / 256, 256, 0, stream>>>(Lvote_w2, wV2, NW);

  // ---- message-passing rounds ----
  for (int r = 0; r < N_ROUNDS; ++r) {
    fused_mlp3<<<N_LITS / 16, 64, 0, stream>>>(
        Lh, wLm1, Lmsg_b1, wLm2, Lmsg_b2, wLm3, Lmsg_b3, T);
    spmm_cls_kernel<<<N_CLAUSES / 4, 256, 0, stream>>>(cls_ptr, cls_col, T, Ch, X);
    gates_lstm<8><<<N_CLAUSES / 32, 256, 0, stream>>>(X, WCp, bC, Cc, Ch);
    fused_mlp3<<<N_CLAUSES / 16, 64, 0, stream>>>(
        Ch, wCm1, Cmsg_b1, wCm2, Cmsg_b2, wCm3, Cmsg_b3, T);
    spmm_lit_kernel<<<N_LITS / 4, 256, 0, stream>>>(lit_ptr, lit_col, T, Lh, X);
    gates_lstm<12><<<N_LITS / 32, 256, 0, stream>>>(X, WLp, bL, Lc, Lh);
  }

  // ---- vote + per-problem mean ----
  fused_vote<<<N_LITS / 64, 256, 0, stream>>>(
      Lh, wV1, Lvote_b1, wV2, Lvote_b2, Lvote_w3, Lvote_b3, vote);
  prob_mean_kernel<<<N_PROBS, 256, 0, stream>>>(vote, out);
}

// Round 4
// 1411.705 us; speedup vs baseline: 2.7490x; 1.1598x over previous
//
#include <hip/hip_runtime.h>
#include <cstdint>
#include <cstddef>

#define N_VARS   4000
#define N_LITS   8000
#define N_CLAUSES 16000
#define N_CELLS  48000
#define DIM      128
#define N_ROUNDS 16
#define N_PROBS  8

typedef __bf16 bf16x8 __attribute__((ext_vector_type(8)));
typedef float f32x4 __attribute__((ext_vector_type(4)));

__device__ inline unsigned short f2bf(float x) {
  unsigned int u = __float_as_uint(x);
  u += 0x7fffu + ((u >> 16) & 1u);          // RTNE
  return (unsigned short)(u >> 16);
}
__device__ inline float bflo(unsigned int v) { return __uint_as_float(v << 16); }
__device__ inline float bfhi(unsigned int v) { return __uint_as_float(v & 0xffff0000u); }
__device__ inline unsigned int pack2(float a, float b) {
  return (unsigned int)f2bf(a) | ((unsigned int)f2bf(b) << 16);
}
__device__ inline bf16x8 ld_frag(const unsigned short* p) {
  uint4 u = *reinterpret_cast<const uint4*>(p);
  return __builtin_bit_cast(bf16x8, u);
}
__device__ inline bf16x8 ld_frag_lds(const unsigned short* p) {
  uint4 u = *reinterpret_cast<const uint4*>(p);
  return __builtin_bit_cast(bf16x8, u);
}
__device__ inline float fast_sigmoid(float x) { return 1.f / (1.f + __expf(-x)); }
__device__ inline float fast_tanh(float x) {
  float t = __expf(-2.f * x);
  return (1.f - t) / (1.f + t);
}

// ===========================================================================
// fused_round<KS, RG, LIT>: one message-passing half-round for ROWS=RG*16 rows.
//   phase 1: msg[ROWS][128] = sum over CSR neighbors of Tsrc rows (LDS, bf16)
//   phase 2: gates[ROWS][512] = [msg | h...] @ Wp^T + bP, fused LSTM update
//            (Wp gate-permuted so lane holds i,f,g,o in its 4 acc regs)
//   phase 3: Tout[rows] = 3-layer MLP(h_new) (h from LDS)
// B-frag sources per ks: ks<4: LDS msg; C-side ks 4-7: Ch[row];
// L-side ks 4-7: Lh_old[flip(row)], ks 8-11: Lh_old[row].
// Block: 256 thr = 4 waves. Wave w owns gate-cols' w*128..+128 in phase 2,
// and (RG==1 ? rows 0-15, col-tiles 2w..2w+1 : rows (w>>1)*16.., tiles (w&1)*4..)
// in phase 3.
// ===========================================================================
template<int KS, int RG, bool LIT>
__global__ __launch_bounds__(256) void fused_round(
    const int* __restrict__ ptr, const int* __restrict__ col,
    const unsigned short* __restrict__ Tsrc,
    const unsigned short* hold, unsigned short* hnew,   // no restrict: may alias (C side)
    float* __restrict__ cst,
    const unsigned short* __restrict__ Wp, const float* __restrict__ bP,
    const unsigned short* __restrict__ Wm1, const float* __restrict__ bm1,
    const unsigned short* __restrict__ Wm2, const float* __restrict__ bm2,
    const unsigned short* __restrict__ Wm3, const float* __restrict__ bm3,
    unsigned short* __restrict__ Tout) {
  constexpr int K = KS * 32;
  constexpr int ROWS = RG * 16;
  __shared__ __align__(16) unsigned short msg[ROWS][136];
  __shared__ __align__(16) unsigned short hb[ROWS][136];
  __shared__ __align__(16) unsigned short xb[ROWS][136];
  const int tid = threadIdx.x;
  const int w = tid >> 6, l = tid & 63;
  const int r = l & 15, kc = l >> 4;
  const int row0 = blockIdx.x * ROWS;

  // ---- phase 1: gather msg ----
  {
    const int g = tid >> 4, gl = tid & 15;
#pragma unroll
    for (int rr = g; rr < ROWS; rr += 16) {
      const int row = row0 + rr;
      const int b = ptr[row], e = ptr[row + 1];
      float s[8] = {0.f, 0.f, 0.f, 0.f, 0.f, 0.f, 0.f, 0.f};
      for (int j = b; j < e; ++j) {
        const uint4 v = *reinterpret_cast<const uint4*>(&Tsrc[(size_t)col[j] * 128 + gl * 8]);
        s[0] += bflo(v.x); s[1] += bfhi(v.x);
        s[2] += bflo(v.y); s[3] += bfhi(v.y);
        s[4] += bflo(v.z); s[5] += bfhi(v.z);
        s[6] += bflo(v.w); s[7] += bfhi(v.w);
      }
      uint4 o;
      o.x = pack2(s[0], s[1]); o.y = pack2(s[2], s[3]);
      o.z = pack2(s[4], s[5]); o.w = pack2(s[6], s[7]);
      *reinterpret_cast<uint4*>(&msg[rr][gl * 8]) = o;
    }
  }
  __syncthreads();

  // ---- phase 2: gates GEMM + LSTM ----
  f32x4 acc[RG][8];
#pragma unroll
  for (int rg = 0; rg < RG; ++rg)
#pragma unroll
    for (int t = 0; t < 8; ++t) acc[rg][t] = (f32x4){0.f, 0.f, 0.f, 0.f};

  const int flipoff = LIT ? ((row0 < N_VARS) ? N_VARS : -N_VARS) : 0;

#pragma unroll
  for (int ks = 0; ks < KS; ++ks) {
    bf16x8 bfr[RG];
#pragma unroll
    for (int rg = 0; rg < RG; ++rg) {
      const int xr = rg * 16 + r;
      if (ks < 4) {
        bfr[rg] = ld_frag_lds(&msg[xr][ks * 32 + kc * 8]);
      } else if (!LIT) {
        bfr[rg] = ld_frag(&hold[(size_t)(row0 + xr) * 128 + (ks - 4) * 32 + kc * 8]);
      } else if (ks < 8) {
        bfr[rg] = ld_frag(&hold[(size_t)(row0 + xr + flipoff) * 128 + (ks - 4) * 32 + kc * 8]);
      } else {
        bfr[rg] = ld_frag(&hold[(size_t)(row0 + xr) * 128 + (ks - 8) * 32 + kc * 8]);
      }
    }
#pragma unroll
    for (int tt = 0; tt < 8; ++tt) {
      bf16x8 afr = ld_frag(&Wp[(size_t)(w * 128 + tt * 16 + r) * K + ks * 32 + kc * 8]);
#pragma unroll
      for (int rg = 0; rg < RG; ++rg)
        acc[rg][tt] = __builtin_amdgcn_mfma_f32_16x16x32_bf16(afr, bfr[rg], acc[rg][tt], 0, 0, 0);
    }
  }

#pragma unroll
  for (int rg = 0; rg < RG; ++rg) {
    const int row = row0 + rg * 16 + r;
    const size_t cb = (size_t)row * 128 + w * 32 + kc * 8;
    f32x4 c0 = *reinterpret_cast<const f32x4*>(&cst[cb]);
    f32x4 c1 = *reinterpret_cast<const f32x4*>(&cst[cb + 4]);
    f32x4 n0, n1;
    unsigned int hp[4];
#pragma unroll
    for (int tt = 0; tt < 8; ++tt) {
      const float4 bb = *reinterpret_cast<const float4*>(&bP[w * 128 + tt * 16 + kc * 4]);
      float ig = acc[rg][tt][0] + bb.x;
      float fg = acc[rg][tt][1] + bb.y;
      float gg = acc[rg][tt][2] + bb.z;
      float og = acc[rg][tt][3] + bb.w;
      float cp = (tt < 4) ? c0[tt] : c1[tt - 4];
      float cn = fast_sigmoid(fg) * cp + fast_sigmoid(ig) * fast_tanh(gg);
      float hv = fast_sigmoid(og) * fast_tanh(cn);
      if (tt < 4) n0[tt] = cn; else n1[tt - 4] = cn;
      if (tt & 1) hp[tt >> 1] |= (unsigned int)f2bf(hv) << 16;
      else        hp[tt >> 1]  = (unsigned int)f2bf(hv);
    }
    *reinterpret_cast<f32x4*>(&cst[cb]) = n0;
    *reinterpret_cast<f32x4*>(&cst[cb + 4]) = n1;
    uint4 hv4 = {hp[0], hp[1], hp[2], hp[3]};
    *reinterpret_cast<uint4*>(&hnew[cb]) = hv4;
    *reinterpret_cast<uint4*>(&hb[rg * 16 + r][w * 32 + kc * 8]) = hv4;
  }
  __syncthreads();

  // ---- phase 3: 3-layer MLP on h (rows of this block) ----
  constexpr int TPW = (RG == 1) ? 2 : 4;
  const int mrg = (RG == 1) ? 0 : (w >> 1);
  const int t0  = (RG == 1) ? (w * 2) : ((w & 1) * 4);

  // layer 1: hb -> xb, relu
  {
    f32x4 a2[TPW];
#pragma unroll
    for (int q = 0; q < TPW; ++q) a2[q] = (f32x4){0.f, 0.f, 0.f, 0.f};
#pragma unroll
    for (int ks = 0; ks < 4; ++ks) {
      bf16x8 af = ld_frag_lds(&hb[mrg * 16 + r][ks * 32 + kc * 8]);
#pragma unroll
      for (int q = 0; q < TPW; ++q) {
        bf16x8 bf = ld_frag(&Wm1[(size_t)((t0 + q) * 16 + r) * 128 + ks * 32 + kc * 8]);
        a2[q] = __builtin_amdgcn_mfma_f32_16x16x32_bf16(af, bf, a2[q], 0, 0, 0);
      }
    }
#pragma unroll
    for (int q = 0; q < TPW; ++q) {
      float bv = bm1[(t0 + q) * 16 + r];
#pragma unroll
      for (int j = 0; j < 4; ++j)
        xb[mrg * 16 + kc * 4 + j][(t0 + q) * 16 + r] = f2bf(fmaxf(a2[q][j] + bv, 0.f));
    }
  }
  __syncthreads();
  // layer 2: xb -> msg (reused), relu
  {
    f32x4 a2[TPW];
#pragma unroll
    for (int q = 0; q < TPW; ++q) a2[q] = (f32x4){0.f, 0.f, 0.f, 0.f};
#pragma unroll
    for (int ks = 0; ks < 4; ++ks) {
      bf16x8 af = ld_frag_lds(&xb[mrg * 16 + r][ks * 32 + kc * 8]);
#pragma unroll
      for (int q = 0; q < TPW; ++q) {
        bf16x8 bf = ld_frag(&Wm2[(size_t)((t0 + q) * 16 + r) * 128 + ks * 32 + kc * 8]);
        a2[q] = __builtin_amdgcn_mfma_f32_16x16x32_bf16(af, bf, a2[q], 0, 0, 0);
      }
    }
#pragma unroll
    for (int q = 0; q < TPW; ++q) {
      float bv = bm2[(t0 + q) * 16 + r];
#pragma unroll
      for (int j = 0; j < 4; ++j)
        msg[mrg * 16 + kc * 4 + j][(t0 + q) * 16 + r] = f2bf(fmaxf(a2[q][j] + bv, 0.f));
    }
  }
  __syncthreads();
  // layer 3: msg -> Tout, linear
  {
    f32x4 a2[TPW];
#pragma unroll
    for (int q = 0; q < TPW; ++q) a2[q] = (f32x4){0.f, 0.f, 0.f, 0.f};
#pragma unroll
    for (int ks = 0; ks < 4; ++ks) {
      bf16x8 af = ld_frag_lds(&msg[mrg * 16 + r][ks * 32 + kc * 8]);
#pragma unroll
      for (int q = 0; q < TPW; ++q) {
        bf16x8 bf = ld_frag(&Wm3[(size_t)((t0 + q) * 16 + r) * 128 + ks * 32 + kc * 8]);
        a2[q] = __builtin_amdgcn_mfma_f32_16x16x32_bf16(af, bf, a2[q], 0, 0, 0);
      }
    }
#pragma unroll
    for (int q = 0; q < TPW; ++q) {
      float bv = bm3[(t0 + q) * 16 + r];
#pragma unroll
      for (int j = 0; j < 4; ++j)
        Tout[(size_t)(row0 + mrg * 16 + kc * 4 + j) * 128 + (t0 + q) * 16 + r] =
            f2bf(a2[q][j] + bv);
    }
  }
}

// ---------------------------------------------------------------------------
// Prologue 3-layer MLP (one wave per 16 rows) — computes initial T_L.
// ---------------------------------------------------------------------------
__global__ __launch_bounds__(64) void fused_mlp3(
    const unsigned short* __restrict__ A,
    const unsigned short* __restrict__ W1, const float* __restrict__ b1,
    const unsigned short* __restrict__ W2, const float* __restrict__ b2,
    const unsigned short* __restrict__ W3, const float* __restrict__ b3,
    unsigned short* __restrict__ out) {
  __shared__ __align__(16) unsigned short xb[16][136];
  const int l = threadIdx.x;
  const int r = l & 15, kc = l >> 4;
  const int row0 = blockIdx.x * 16;

  f32x4 acc[8];
#pragma unroll
  for (int t = 0; t < 8; ++t) acc[t] = (f32x4){0.f, 0.f, 0.f, 0.f};
#pragma unroll
  for (int ks = 0; ks < 4; ++ks) {
    bf16x8 a = ld_frag(&A[(size_t)(row0 + r) * 128 + ks * 32 + kc * 8]);
#pragma unroll
    for (int t = 0; t < 8; ++t) {
      bf16x8 b = ld_frag(&W1[(size_t)(t * 16 + r) * 128 + ks * 32 + kc * 8]);
      acc[t] = __builtin_amdgcn_mfma_f32_16x16x32_bf16(a, b, acc[t], 0, 0, 0);
    }
  }
#pragma unroll
  for (int t = 0; t < 8; ++t) {
    float bv = b1[t * 16 + r];
#pragma unroll
    for (int j = 0; j < 4; ++j)
      xb[kc * 4 + j][t * 16 + r] = f2bf(fmaxf(acc[t][j] + bv, 0.f));
  }
  __syncthreads();
#pragma unroll
  for (int t = 0; t < 8; ++t) acc[t] = (f32x4){0.f, 0.f, 0.f, 0.f};
#pragma unroll
  for (int ks = 0; ks < 4; ++ks) {
    bf16x8 a = ld_frag(&xb[r][ks * 32 + kc * 8]);
#pragma unroll
    for (int t = 0; t < 8; ++t) {
      bf16x8 b = ld_frag(&W2[(size_t)(t * 16 + r) * 128 + ks * 32 + kc * 8]);
      acc[t] = __builtin_amdgcn_mfma_f32_16x16x32_bf16(a, b, acc[t], 0, 0, 0);
    }
  }
  __syncthreads();
#pragma unroll
  for (int t = 0; t < 8; ++t) {
    float bv = b2[t * 16 + r];
#pragma unroll
    for (int j = 0; j < 4; ++j)
      xb[kc * 4 + j][t * 16 + r] = f2bf(fmaxf(acc[t][j] + bv, 0.f));
  }
  __syncthreads();
#pragma unroll
  for (int t = 0; t < 8; ++t) acc[t] = (f32x4){0.f, 0.f, 0.f, 0.f};
#pragma unroll
  for (int ks = 0; ks < 4; ++ks) {
    bf16x8 a = ld_frag(&xb[r][ks * 32 + kc * 8]);
#pragma unroll
    for (int t = 0; t < 8; ++t) {
      bf16x8 b = ld_frag(&W3[(size_t)(t * 16 + r) * 128 + ks * 32 + kc * 8]);
      acc[t] = __builtin_amdgcn_mfma_f32_16x16x32_bf16(a, b, acc[t], 0, 0, 0);
    }
  }
#pragma unroll
  for (int t = 0; t < 8; ++t) {
    float bv = b3[t * 16 + r];
#pragma unroll
    for (int j = 0; j < 4; ++j)
      out[(size_t)(row0 + kc * 4 + j) * 128 + t * 16 + r] = f2bf(acc[t][j] + bv);
  }
}

// ---------------------------------------------------------------------------
// Fused vote: relu(relu(A@W1^T+b1)@W2^T+b2) . w3 + b3 -> vote[M] (fp32)
// ---------------------------------------------------------------------------
__global__ __launch_bounds__(256) void fused_vote(
    const unsigned short* __restrict__ A,
    const unsigned short* __restrict__ W1, const float* __restrict__ b1,
    const unsigned short* __restrict__ W2, const float* __restrict__ b2,
    const float* __restrict__ w3, const float* __restrict__ b3,
    float* __restrict__ vote) {
  __shared__ __align__(16) unsigned short xbuf[4][16][136];
  const int w = threadIdx.x >> 6, l = threadIdx.x & 63;
  const int r = l & 15, kc = l >> 4;
  const int row0 = blockIdx.x * 64 + w * 16;

  f32x4 acc[8];
#pragma unroll
  for (int t = 0; t < 8; ++t) acc[t] = (f32x4){0.f, 0.f, 0.f, 0.f};
#pragma unroll
  for (int ks = 0; ks < 4; ++ks) {
    bf16x8 a = ld_frag(&A[(size_t)(row0 + r) * 128 + ks * 32 + kc * 8]);
#pragma unroll
    for (int t = 0; t < 8; ++t) {
      bf16x8 b = ld_frag(&W1[(size_t)(t * 16 + r) * 128 + ks * 32 + kc * 8]);
      acc[t] = __builtin_amdgcn_mfma_f32_16x16x32_bf16(a, b, acc[t], 0, 0, 0);
    }
  }
#pragma unroll
  for (int t = 0; t < 8; ++t) {
    float bv = b1[t * 16 + r];
#pragma unroll
    for (int j = 0; j < 4; ++j)
      xbuf[w][kc * 4 + j][t * 16 + r] = f2bf(fmaxf(acc[t][j] + bv, 0.f));
  }
#pragma unroll
  for (int t = 0; t < 8; ++t) acc[t] = (f32x4){0.f, 0.f, 0.f, 0.f};
#pragma unroll
  for (int ks = 0; ks < 4; ++ks) {
    bf16x8 a = ld_frag(&xbuf[w][r][ks * 32 + kc * 8]);
#pragma unroll
    for (int t = 0; t < 8; ++t) {
      bf16x8 b = ld_frag(&W2[(size_t)(t * 16 + r) * 128 + ks * 32 + kc * 8]);
      acc[t] = __builtin_amdgcn_mfma_f32_16x16x32_bf16(a, b, acc[t], 0, 0, 0);
    }
  }
  float vs[4] = {0.f, 0.f, 0.f, 0.f};
#pragma unroll
  for (int t = 0; t < 8; ++t) {
    float bv = b2[t * 16 + r], wv = w3[t * 16 + r];
#pragma unroll
    for (int j = 0; j < 4; ++j)
      vs[j] += fmaxf(acc[t][j] + bv, 0.f) * wv;
  }
#pragma unroll
  for (int off = 1; off < 16; off <<= 1) {
#pragma unroll
    for (int j = 0; j < 4; ++j) vs[j] += __shfl_xor(vs[j], off, 16);
  }
  if (r == 0) {
#pragma unroll
    for (int j = 0; j < 4; ++j) vote[row0 + kc * 4 + j] = vs[j] + b3[0];
  }
}

// ---------------------------------------------------------------------------
// One-time prep.
// ---------------------------------------------------------------------------
__global__ void init_state_kernel(const float* __restrict__ Lw, const float* __restrict__ Lb,
                                  const float* __restrict__ Cw, const float* __restrict__ Cb,
                                  unsigned short* __restrict__ Lh, float* __restrict__ Lc,
                                  unsigned short* __restrict__ Ch, float* __restrict__ Cc) {
  int idx = blockIdx.x * 256 + threadIdx.x;
  if (idx >= N_CLAUSES * DIM) return;
  int d = idx & 127;
  Ch[idx] = f2bf(Cw[d] + Cb[d]);
  Cc[idx] = 0.f;
  if (idx < N_LITS * DIM) {
    Lh[idx] = f2bf(Lw[d] + Lb[d]);
    Lc[idx] = 0.f;
  }
}

// 8 fp32->bf16 weight conversions in one launch (grid.y selects matrix).
__global__ void cvt8_kernel(const float* s0, const float* s1, const float* s2, const float* s3,
                            const float* s4, const float* s5, const float* s6, const float* s7,
                            unsigned short* d0, unsigned short* d1, unsigned short* d2,
                            unsigned short* d3, unsigned short* d4, unsigned short* d5,
                            unsigned short* d6, unsigned short* d7) {
  int i = blockIdx.x * 256 + threadIdx.x;
  const float* s; unsigned short* d;
  switch (blockIdx.y) {
    case 0: s = s0; d = d0; break;
    case 1: s = s1; d = d1; break;
    case 2: s = s2; d = d2; break;
    case 3: s = s3; d = d3; break;
    case 4: s = s4; d = d4; break;
    case 5: s = s5; d = d5; break;
    case 6: s = s6; d = d6; break;
    default: s = s7; d = d7; break;
  }
  d[i] = f2bf(s[i]);
}

// W' pack with gate-interleaved row permutation (see fused_round comment).
// n' -> orig row: gt = n'&3, d = (n'>>7)*32 + ((n'>>2)&3)*8 + ((n'>>4)&7).
template<int KIH>
__global__ void pack_gates_kernel(const float* __restrict__ wih, const float* __restrict__ whh,
                                  const float* __restrict__ bih, const float* __restrict__ bhh,
                                  unsigned short* __restrict__ Wp, float* __restrict__ bP) {
  constexpr int K = KIH + 128;
  int idx = blockIdx.x * 256 + threadIdx.x;
  if (idx >= 512 * K) return;
  int np = idx / K, k = idx % K;
  int gt = np & 3;
  int d = ((np >> 7) << 5) + (((np >> 2) & 3) << 3) + ((np >> 4) & 7);
  int orig = gt * 128 + d;
  float v = (k < KIH) ? wih[(size_t)orig * KIH + k] : whh[(size_t)orig * 128 + (k - KIH)];
  Wp[idx] = f2bf(v);
  if (k == 0) bP[np] = bih[orig] + bhh[orig];
}

// ---------------------------------------------------------------------------
// CSR build.
// ---------------------------------------------------------------------------
__global__ void count_kernel(const int* __restrict__ uidx,
                             int* __restrict__ lit_cnt, int* __restrict__ cls_cnt) {
  int i = blockIdx.x * 256 + threadIdx.x;
  if (i < N_CELLS) {
    atomicAdd(&lit_cnt[uidx[2 * i]], 1);
    atomicAdd(&cls_cnt[uidx[2 * i + 1]], 1);
  }
}

__global__ void scan_kernel(const int* __restrict__ cnt, int* __restrict__ ptr, int n) {
  __shared__ int part[1024];
  __shared__ int total;
  int t = threadIdx.x;
  int chunk = (n + 1023) >> 10;
  int lo = t * chunk, hi = min(lo + chunk, n);
  int s = 0;
  for (int i = lo; i < hi; ++i) s += cnt[i];
  part[t] = s;
  __syncthreads();
  if (t == 0) {
    int acc = 0;
    for (int i = 0; i < 1024; ++i) { int v = part[i]; part[i] = acc; acc += v; }
    total = acc;
  }
  __syncthreads();
  int acc = part[t];
  for (int i = lo; i < hi; ++i) { ptr[i] = acc; acc += cnt[i]; }
  if (t == 0) ptr[n] = total;
}

__global__ void scatter_kernel(const int* __restrict__ uidx,
                               const int* __restrict__ lit_ptr, const int* __restrict__ cls_ptr,
                               int* __restrict__ lit_fill, int* __restrict__ cls_fill,
                               int* __restrict__ lit_col, int* __restrict__ cls_col) {
  int i = blockIdx.x * 256 + threadIdx.x;
  if (i < N_CELLS) {
    int lit = uidx[2 * i], cls = uidx[2 * i + 1];
    int p = atomicAdd(&lit_fill[lit], 1);
    lit_col[lit_ptr[lit] + p] = cls;
    int q = atomicAdd(&cls_fill[cls], 1);
    cls_col[cls_ptr[cls] + q] = lit;
  }
}

__global__ void prob_mean_kernel(const float* __restrict__ vote, float* __restrict__ out) {
  int p = blockIdx.x;
  int t = threadIdx.x;
  float s = 0.f;
  for (int i = t; i < 500; i += 256) s += vote[p * 500 + i] + vote[N_VARS + p * 500 + i];
  __shared__ float red[256];
  red[t] = s;
  __syncthreads();
  for (int off = 128; off > 0; off >>= 1) {
    if (t < off) red[t] += red[t + off];
    __syncthreads();
  }
  if (t == 0) out[p] = red[0] * (1.0f / 1000.0f);
}

// ---------------------------------------------------------------------------
extern "C" void kernel_launch(void* const* d_in, const int* in_sizes, int n_in,
                              void* d_out, int out_size, void* d_ws, size_t ws_size,
                              hipStream_t stream) {
  (void)in_sizes; (void)n_in; (void)out_size;
  const int* uidx = (const int*)d_in[0];
  const float* L_init_w = (const float*)d_in[4];
  const float* L_init_b = (const float*)d_in[5];
  const float* C_init_w = (const float*)d_in[6];
  const float* C_init_b = (const float*)d_in[7];
  const float* Lmsg_w1 = (const float*)d_in[8],  *Lmsg_b1 = (const float*)d_in[9];
  const float* Lmsg_w2 = (const float*)d_in[10], *Lmsg_b2 = (const float*)d_in[11];
  const float* Lmsg_w3 = (const float*)d_in[12], *Lmsg_b3 = (const float*)d_in[13];
  const float* Cmsg_w1 = (const float*)d_in[14], *Cmsg_b1 = (const float*)d_in[15];
  const float* Cmsg_w2 = (const float*)d_in[16], *Cmsg_b2 = (const float*)d_in[17];
  const float* Cmsg_w3 = (const float*)d_in[18], *Cmsg_b3 = (const float*)d_in[19];
  const float* Lvote_w1 = (const float*)d_in[20], *Lvote_b1 = (const float*)d_in[21];
  const float* Lvote_w2 = (const float*)d_in[22], *Lvote_b2 = (const float*)d_in[23];
  const float* Lvote_w3 = (const float*)d_in[24], *Lvote_b3 = (const float*)d_in[25];
  const float* Lu_wih = (const float*)d_in[26], *Lu_whh = (const float*)d_in[27];
  const float* Lu_bih = (const float*)d_in[28], *Lu_bhh = (const float*)d_in[29];
  const float* Cu_wih = (const float*)d_in[30], *Cu_whh = (const float*)d_in[31];
  const float* Cu_bih = (const float*)d_in[32], *Cu_bhh = (const float*)d_in[33];
  float* out = (float*)d_out;

  // ---- workspace carve-up ----
  char* base = (char*)d_ws;
  size_t off = 0;
  auto alloc = [&](size_t bytes) {
    void* p = base + off;
    off = (off + bytes + 255) & ~(size_t)255;
    return p;
  };
  float* Lc   = (float*)alloc((size_t)N_LITS * DIM * 4);
  float* Cc   = (float*)alloc((size_t)N_CLAUSES * DIM * 4);
  float* bL   = (float*)alloc(512 * 4);
  float* bC   = (float*)alloc(512 * 4);
  float* vote = (float*)alloc(N_LITS * 4);
  unsigned short* LhA = (unsigned short*)alloc((size_t)N_LITS * DIM * 2);
  unsigned short* LhB = (unsigned short*)alloc((size_t)N_LITS * DIM * 2);
  unsigned short* Ch  = (unsigned short*)alloc((size_t)N_CLAUSES * DIM * 2);
  unsigned short* TL  = (unsigned short*)alloc((size_t)N_LITS * DIM * 2);
  unsigned short* TC  = (unsigned short*)alloc((size_t)N_CLAUSES * DIM * 2);
  unsigned short* WLp = (unsigned short*)alloc(512 * 384 * 2);
  unsigned short* WCp = (unsigned short*)alloc(512 * 256 * 2);
  unsigned short* wLm1 = (unsigned short*)alloc(DIM * DIM * 2);
  unsigned short* wLm2 = (unsigned short*)alloc(DIM * DIM * 2);
  unsigned short* wLm3 = (unsigned short*)alloc(DIM * DIM * 2);
  unsigned short* wCm1 = (unsigned short*)alloc(DIM * DIM * 2);
  unsigned short* wCm2 = (unsigned short*)alloc(DIM * DIM * 2);
  unsigned short* wCm3 = (unsigned short*)alloc(DIM * DIM * 2);
  unsigned short* wV1  = (unsigned short*)alloc(DIM * DIM * 2);
  unsigned short* wV2  = (unsigned short*)alloc(DIM * DIM * 2);
  int* lit_cnt  = (int*)alloc(N_LITS * 4);
  int* cls_cnt  = (int*)alloc(N_CLAUSES * 4);
  int* lit_fill = (int*)alloc(N_LITS * 4);
  int* cls_fill = (int*)alloc(N_CLAUSES * 4);
  int* lit_ptr  = (int*)alloc((N_LITS + 1) * 4);
  int* cls_ptr  = (int*)alloc((N_CLAUSES + 1) * 4);
  int* lit_col  = (int*)alloc(N_CELLS * 4);
  int* cls_col  = (int*)alloc(N_CELLS * 4);
  if (off > ws_size) return;

  // ---- CSR build (redone every launch) ----
  hipMemsetAsync(lit_cnt, 0, (char*)lit_ptr - (char*)lit_cnt, stream);
  count_kernel<<<(N_CELLS + 255) / 256, 256, 0, stream>>>(uidx, lit_cnt, cls_cnt);
  scan_kernel<<<1, 1024, 0, stream>>>(lit_cnt, lit_ptr, N_LITS);
  scan_kernel<<<1, 1024, 0, stream>>>(cls_cnt, cls_ptr, N_CLAUSES);
  scatter_kernel<<<(N_CELLS + 255) / 256, 256, 0, stream>>>(
      uidx, lit_ptr, cls_ptr, lit_fill, cls_fill, lit_col, cls_col);

  // ---- one-time weight conversion / packing / state init ----
  init_state_kernel<<<(N_CLAUSES * DIM + 255) / 256, 256, 0, stream>>>(
      L_init_w, L_init_b, C_init_w, C_init_b, LhA, Lc, Ch, Cc);
  pack_gates_kernel<256><<<(512 * 384 + 255) / 256, 256, 0, stream>>>(
      Lu_wih, Lu_whh, Lu_bih, Lu_bhh, WLp, bL);
  pack_gates_kernel<128><<<(512 * 256 + 255) / 256, 256, 0, stream>>>(
      Cu_wih, Cu_whh, Cu_bih, Cu_bhh, WCp, bC);
  dim3 cgrid(DIM * DIM / 256, 8);
  cvt8_kernel<<<cgrid, 256, 0, stream>>>(
      Lmsg_w1, Lmsg_w2, Lmsg_w3, Cmsg_w1, Cmsg_w2, Cmsg_w3, Lvote_w1, Lvote_w2,
      wLm1, wLm2, wLm3, wCm1, wCm2, wCm3, wV1, wV2);

  // ---- prologue: T_L = L-MLP(Lh0) ----
  fused_mlp3<<<N_LITS / 16, 64, 0, stream>>>(
      LhA, wLm1, Lmsg_b1, wLm2, Lmsg_b2, wLm3, Lmsg_b3, TL);

  // ---- message-passing rounds: 2 kernels per round ----
  for (int r = 0; r < N_ROUNDS; ++r) {
    fused_round<8, 2, false><<<N_CLAUSES / 32, 256, 0, stream>>>(
        cls_ptr, cls_col, TL, Ch, Ch, Cc, WCp, bC,
        wCm1, Cmsg_b1, wCm2, Cmsg_b2, wCm3, Cmsg_b3, TC);
    const unsigned short* lold = (r & 1) ? LhB : LhA;
    unsigned short* lnew = (r & 1) ? LhA : LhB;
    fused_round<12, 1, true><<<N_LITS / 16, 256, 0, stream>>>(
        lit_ptr, lit_col, TC, lold, lnew, Lc, WLp, bL,
        wLm1, Lmsg_b1, wLm2, Lmsg_b2, wLm3, Lmsg_b3, TL);
  }
  // after 16 rounds (even count), final Lh is in LhA

  // ---- vote + per-problem mean ----
  fused_vote<<<N_LITS / 64, 256, 0, stream>>>(
      LhA, wV1, Lvote_b1, wV2, Lvote_b2, Lvote_w3, Lvote_b3, vote);
  prob_mean_kernel<<<N_PROBS, 256, 0, stream>>>(vote, out);
}